// Round 13
// baseline (111.617 us; speedup 1.0000x reference)
//
#include <hip/hip_runtime.h>

typedef __attribute__((ext_vector_type(8))) short short8;
typedef __attribute__((ext_vector_type(4))) short short4v;
typedef __attribute__((ext_vector_type(4))) float f32x4;
typedef __attribute__((ext_vector_type(16))) float f32x16;
typedef __attribute__((ext_vector_type(2))) unsigned uint2v;
typedef __attribute__((ext_vector_type(4))) unsigned uint4v;

#define MFMA16(a,b,c) __builtin_amdgcn_mfma_f32_16x16x32_bf16((a),(b),(c),0,0,0)
#define MFMA32(a,b,c) __builtin_amdgcn_mfma_f32_32x32x16_bf16((a),(b),(c),0,0,0)

#define BB 32
#define SS 1024
#define DD 192
#define HH 8
#define DHP 32   // padded head dim (24 -> 32); col 31 = mask-bias, col 24 of V = ones

// Q pre-scale: log2(e) / sqrt(24)  -> exp2(S) == softmax numerator
#define SCALE_Q 0.294468266742895f

// native RNE conversions (compiler emits v_cvt_*_bf16, fuses pairs to cvt_pk)
__device__ __forceinline__ short nb(float f) {
    __bf16 h = (__bf16)f;
    return __builtin_bit_cast(short, h);
}
__device__ __forceinline__ float bf2f(short s) {
    union { unsigned u; float f; } v; v.u = ((unsigned)(unsigned short)s) << 16;
    return v.f;
}
__device__ __forceinline__ unsigned pk2(float a, float b) {
    unsigned short lo = __builtin_bit_cast(unsigned short, (__bf16)a);
    unsigned short hi = __builtin_bit_cast(unsigned short, (__bf16)b);
    return (unsigned)lo | ((unsigned)hi << 16);
}

// ---------------- prep: fragment-order weight layouts ----------------
__global__ __launch_bounds__(256) void prep_kernel(
    const float* __restrict__ Wq, const float* __restrict__ Wk, const float* __restrict__ Wv,
    const float* __restrict__ Wo,
    short* __restrict__ WqF, short* __restrict__ WkF, short* __restrict__ WvF,
    short* __restrict__ WoFh, short* __restrict__ WoFl)
{
    int idx = blockIdx.x * 256 + threadIdx.x;
    const int NWX   = 3 * HH * DHP * DD;     // 147456
    const int NWO   = DD * DD;               // 36864
    if (idx < NWX) {
        int j = idx;
        int mat = j / (HH * DHP * DD);
        int jj  = j % (HH * DHP * DD);
        int h   = jj / (DHP * DD);
        int rem = jj % (DHP * DD);
        int e   = rem / DD;       // actual output col 0..31
        int d   = rem % DD;       // input dim
        const float* W = (mat == 0) ? Wq : (mat == 1) ? Wk : Wv;
        short* WF      = (mat == 0) ? WqF : (mat == 1) ? WkF : WvF;
        float val = (e < 24) ? W[(h * DD + d) * 24 + e] : 0.f;   // pad e>=24 with 0
        int nt = e & 1, cc = e >> 1;
        int kk = d >> 5, g = (d >> 3) & 3, ee = d & 7;
        WF[(size_t)((((h*2+nt)*6 + kk)*64) + g*16 + cc)*8 + ee] = nb(val);
    } else if (idx < NWX + NWO) {
        int j = idx - NWX;
        int n = j / DD, k = j % DD;    // n = out col, k = in dim
        float f = Wo[k * DD + n];
        short hi = nb(f);
        int nn = n >> 4, cc = n & 15;
        int kk = k >> 5, g = (k >> 3) & 3, ee = k & 7;
        size_t addr = (size_t)(((nn*6 + kk)*64) + g*16 + cc)*8 + ee;
        WoFh[addr] = hi;
        WoFl[addr] = nb(f - bf2f(hi));   // split-bf16 low part
    }
}

// ---------------- scan: mask normalize + per-batch compaction map ----------------
// inv[b][s]: unmasked rows -> 0..cnt-1 (stable order); masked rows -> cnt..1023
__global__ __launch_bounds__(1024) void scan_kernel(
    const void* __restrict__ mask_raw,
    float* __restrict__ maskf, int* __restrict__ inv, int* __restrict__ cnt)
{
    int b = blockIdx.x, t = threadIdx.x;
    int lane = t & 63, wv = t >> 6;
    int idx = b * SS + t;

    // dtype sniff: bool may arrive as int32 (0/1), float32 (0.0/1.0) or uint8
    const unsigned* mw = (const unsigned*)mask_raw;
    bool all01 = true, allf = true;
    #pragma unroll
    for (int i = 0; i < 16; i++) {
        unsigned w = mw[i];
        all01 = all01 && (w <= 1u);
        allf  = allf  && (w == 0u || w == 0x3F800000u);
    }
    bool m;
    if (all01)      m = (mw[idx] != 0u);
    else if (allf)  m = (((const float*)mask_raw)[idx] != 0.f);
    else            m = (((const unsigned char*)mask_raw)[idx] != 0);
    maskf[idx] = m ? 1.f : 0.f;

    unsigned long long bal = __ballot(m);
    int preU  = __popcll(bal & ((1ull << lane) - 1ull));
    int waveU = __popcll(bal);
    __shared__ int wsu[16];
    if (lane == 0) wsu[wv] = waveU;
    __syncthreads();
    int waveOffU = 0, totalU = 0;
    #pragma unroll
    for (int i = 0; i < 16; i++) {
        int v = wsu[i];
        if (i < wv) waveOffU += v;
        totalU += v;
    }
    int posU = waveOffU + preU;
    int posM = totalU + (wv * 64 - waveOffU) + (lane - preU);
    inv[idx] = m ? posU : posM;
    if (t == 0) cnt[b] = totalU;
}

// ---------------- proj: Q/K/V = x @ W + b via MFMA (coalesced weight frags) ----------------
// blockIdx.y = head-pair — 2048 blocks = 8/CU for latency hiding.
// Q natural order; K in fragment-tile order KF at compacted row; Vc compacted natural.
// Q[:,31] = 1.0; K[:,31] = mask ? 0 : -1e30; Vc[:,24] = 1.0 (denominator column)
// KF element (kpos,e) -> tile=kpos>>5, instr=e>>4, lane=((e>>3)&1)*32+(kpos&31), j=e&7
__global__ __launch_bounds__(256) void proj_kernel(
    const float* __restrict__ x,
    const float* __restrict__ bq, const float* __restrict__ bk, const float* __restrict__ bv,
    const short* __restrict__ WqF, const short* __restrict__ WkF, const short* __restrict__ WvF,
    const float* __restrict__ maskf, const int* __restrict__ inv,
    short* __restrict__ Q, short* __restrict__ KF, short* __restrict__ Vc)
{
    int tid = threadIdx.x;
    int lane = tid & 63, w = tid >> 6;
    int c = lane & 15, g = lane >> 4;
    int r0 = blockIdx.x * 64 + w * 16;
    int arow = r0 + c;
    int h0 = blockIdx.y * 2;

    // output row block for this thread: rows s0..s0+3 (same batch: 64 | 1024)
    int b_ = r0 >> 10;
    int s0 = (r0 & 1023) + g * 4;

    short8 a[6];
    #pragma unroll
    for (int kk = 0; kk < 6; kk++) {
        const float* px = x + (size_t)arow * DD + kk * 32 + g * 8;
        float4 f0 = *(const float4*)px;
        float4 f1 = *(const float4*)(px + 4);
        short8 t;
        t[0]=nb(f0.x); t[1]=nb(f0.y); t[2]=nb(f0.z); t[3]=nb(f0.w);
        t[4]=nb(f1.x); t[5]=nb(f1.y); t[6]=nb(f1.z); t[7]=nb(f1.w);
        a[kk] = t;
    }

    float mrow[4];
    int dst[4];
    #pragma unroll
    for (int r = 0; r < 4; r++) {
        mrow[r] = maskf[b_ * SS + s0 + r];
        dst[r]  = inv[b_ * SS + s0 + r];
    }

    #pragma unroll
    for (int hh = 0; hh < 2; hh++) {
        int h = h0 + hh;
        int bh = b_ * HH + h;
        #pragma unroll
        for (int mat = 0; mat < 3; mat++) {
            const short* WF   = (mat==0)?WqF:(mat==1)?WkF:WvF;
            const float* bias = (mat==0)?bq:(mat==1)?bk:bv;

            f32x4 acc0 = {0.f,0.f,0.f,0.f};   // actual col 2c
            f32x4 acc1 = {0.f,0.f,0.f,0.f};   // actual col 2c+1
            const short* Wp0 = WF + (size_t)((h*2+0)*6) * 512 + lane * 8;
            const short* Wp1 = WF + (size_t)((h*2+1)*6) * 512 + lane * 8;
            #pragma unroll
            for (int kk = 0; kk < 6; kk++) {
                short8 b0 = *(const short8*)(Wp0 + kk * 512);
                short8 b1 = *(const short8*)(Wp1 + kk * 512);
                acc0 = MFMA16(a[kk], b0, acc0);
                acc1 = MFMA16(a[kk], b1, acc1);
            }
            float bv0 = 0.f, bv1 = 0.f;
            if (2*c < 24) {
                float2 bb = *(const float2*)(bias + h * 24 + 2 * c);
                bv0 = bb.x; bv1 = bb.y;
            }

            if (mat == 0) {
                #pragma unroll
                for (int r = 0; r < 4; r++) {
                    float v0 = (acc0[r] + bv0) * SCALE_Q;
                    float v1 = (c == 15) ? 1.0f : (acc1[r] + bv1) * SCALE_Q;
                    *(unsigned*)(Q + ((size_t)bh * SS + s0 + r) * DHP + 2*c) = pk2(v0, v1);
                }
            } else if (mat == 1) {
                #pragma unroll
                for (int r = 0; r < 4; r++) {
                    float v0 = acc0[r] + bv0;
                    float v1 = (c == 15) ? ((mrow[r] != 0.f) ? 0.f : -1e30f)
                                         : (acc1[r] + bv1);
                    int d = dst[r];
                    size_t koff = (size_t)bh * SS * DHP + (size_t)(d >> 5) * 1024
                                + (size_t)(c >> 3) * 512
                                + (size_t)((((c >> 2) & 1) * 32) + (d & 31)) * 8
                                + ((2 * c) & 7);
                    *(unsigned*)(KF + koff) = pk2(v0, v1);
                }
            } else {
                #pragma unroll
                for (int r = 0; r < 4; r++) {
                    float v0 = (c == 12) ? 1.0f : (acc0[r] + bv0);  // col 24 = ones
                    float v1 = acc1[r] + bv1;
                    *(unsigned*)(Vc + ((size_t)bh * SS + dst[r]) * DHP + 2*c) = pk2(v0, v1);
                }
            }
        }
    }
}

// ---------------- vtrans: Vc[s_c][e] -> VF fragment-tile order ----------------
// VF element (kpos,e) -> tile=kpos>>5, instr=kpos>>4&1, lane=(((kpos>>3)&1)*32+e), j=kpos&7
__global__ __launch_bounds__(256) void vtrans_kernel(
    const short* __restrict__ Vc, short* __restrict__ VF)
{
    __shared__ short tile[256][33];
    int bh = blockIdx.x, c4 = blockIdx.y;
    int t = threadIdx.x;
    const short* src = Vc + ((size_t)bh * SS + c4 * 256 + t) * DHP;
    short8 a0 = *(const short8*)(src);
    short8 a1 = *(const short8*)(src + 8);
    short8 a2 = *(const short8*)(src + 16);
    short8 a3 = *(const short8*)(src + 24);
    #pragma unroll
    for (int i = 0; i < 8; i++) {
        tile[t][i]      = a0[i];
        tile[t][8 + i]  = a1[i];
        tile[t][16 + i] = a2[i];
        tile[t][24 + i] = a3[i];
    }
    __syncthreads();
    int L = t & 63, q = t >> 6;
    int l31 = L & 31, hi = L >> 5;
    short* outb = VF + (size_t)bh * SS * DHP + (size_t)c4 * 8192;   // 8 tiles x 1024
    #pragma unroll
    for (int jj = 0; jj < 4; jj++) {
        int job = q * 4 + jj;          // 0..15
        int tt = job >> 1, ii = job & 1;
        short8 o;
        #pragma unroll
        for (int j = 0; j < 8; j++)
            o[j] = tile[tt * 32 + ii * 16 + hi * 8 + j][l31];
        *(short8*)(outb + (size_t)tt * 1024 + ii * 512 + (size_t)L * 8) = o;
    }
}

// ---------------- flash attention (swapped QK^T, in-register softmax) ----------------
__device__ __forceinline__ void fproc(const f32x16& S, f32x16& acc,
                                      short8 v0, short8 v1)
{
    float p[16];
    #pragma unroll
    for (int r = 0; r < 16; r++) p[r] = __builtin_amdgcn_exp2f(S[r]);

    unsigned c01 = pk2(p[0],  p[1]);
    unsigned c23 = pk2(p[2],  p[3]);
    unsigned c45 = pk2(p[4],  p[5]);
    unsigned c67 = pk2(p[6],  p[7]);
    unsigned c89 = pk2(p[8],  p[9]);
    unsigned cab = pk2(p[10], p[11]);
    unsigned ccd = pk2(p[12], p[13]);
    unsigned cef = pk2(p[14], p[15]);

    // permlane32_swap(a,b): x[l] = l<32 ? a[l] : b[l-32]
    //                       y[l] = l<32 ? a[l+32] : b[l]
    uint2v s0 = __builtin_amdgcn_permlane32_swap(c01, c45, false, false);
    uint2v s1 = __builtin_amdgcn_permlane32_swap(c23, c67, false, false);
    uint2v s2 = __builtin_amdgcn_permlane32_swap(c89, ccd, false, false);
    uint2v s3 = __builtin_amdgcn_permlane32_swap(cab, cef, false, false);

    uint4v w0v = { s0.x, s1.x, s0.y, s1.y };   // PV A-frag, kpos tile 0..15
    uint4v w1v = { s2.x, s3.x, s2.y, s3.y };   // kpos tile 16..31
    short8 pa0 = __builtin_bit_cast(short8, w0v);
    short8 pa1 = __builtin_bit_cast(short8, w1v);

    acc = MFMA32(pa0, v0, acc);
    acc = MFMA32(pa1, v1, acc);
}

// grid 1024 = 256 bh x 4 qb; 2 q-chunks (A at qr, B at qr+128) per wave
// K/V loads are contiguous 1KB fragment-tile loads (base + lane*16B),
// register-double-buffered: tile kt+1 issued before computing tile kt.
__global__ __launch_bounds__(256) void flash_kernel(
    const short* __restrict__ Q, const short* __restrict__ KF, const short* __restrict__ VF,
    const int* __restrict__ cnt, short* __restrict__ Af)
{
    __shared__ float llds[4][2][32];

    int idx = blockIdx.x;
    int bh = idx & 255;
    int qb = idx >> 8;          // 0..3
    int b = bh >> 3, h = bh & 7;

    int tid = threadIdx.x;
    int lane = tid & 63, w = tid >> 6;
    int l31 = lane & 31;
    int hi = lane >> 5;

    int nt = (cnt[b] + 31) >> 5;   // only tiles containing unmasked positions

    int qrA = qb * 256 + w * 32;
    int qrB = qrA + 128;

    const short* QpA = Q + ((size_t)bh * SS + qrA + l31) * DHP + hi * 8;
    const short* QpB = Q + ((size_t)bh * SS + qrB + l31) * DHP + hi * 8;
    short8 qA0 = *(const short8*)QpA;
    short8 qA1 = *(const short8*)(QpA + 16);
    short8 qB0 = *(const short8*)QpB;
    short8 qB1 = *(const short8*)(QpB + 16);

    const short* Kp = KF + (size_t)bh * SS * DHP + (size_t)lane * 8;
    const short* Vp = VF + (size_t)bh * SS * DHP + (size_t)lane * 8;

    f32x16 accA, accB, Z16;
    #pragma unroll
    for (int r = 0; r < 16; r++) { accA[r] = 0.f; accB[r] = 0.f; Z16[r] = 0.f; }

    // prologue: load tile 0
    short8 k0 = *(const short8*)(Kp);
    short8 k1 = *(const short8*)(Kp + 512);
    short8 v0 = *(const short8*)(Vp);
    short8 v1 = *(const short8*)(Vp + 512);

    for (int kt = 0; kt < nt; kt++) {
        // prefetch tile kt+1 (last iteration reads adjacent ws — valid, unused)
        Kp += 1024;
        Vp += 1024;
        short8 nk0 = *(const short8*)(Kp);
        short8 nk1 = *(const short8*)(Kp + 512);
        short8 nv0 = *(const short8*)(Vp);
        short8 nv1 = *(const short8*)(Vp + 512);

        f32x16 SA = MFMA32(k0, qA0, Z16);
        SA = MFMA32(k1, qA1, SA);   // includes mask bias via channel e=31
        f32x16 SB = MFMA32(k0, qB0, Z16);
        SB = MFMA32(k1, qB1, SB);

        fproc(SA, accA, v0, v1);
        fproc(SB, accB, v0, v1);

        k0 = nk0; k1 = nk1; v0 = nv0; v1 = nv1;
    }

    // denominator via V's ones-column: acc col 24 (lanes l31==24)
    if (l31 == 24) {
        #pragma unroll
        for (int r = 0; r < 16; r++) {
            int row = (r & 3) + 8 * (r >> 2) + 4 * hi;
            llds[w][0][row] = __builtin_amdgcn_rcpf(accA[r]);
            llds[w][1][row] = __builtin_amdgcn_rcpf(accB[r]);
        }
    }
    __builtin_amdgcn_wave_barrier();   // same-wave LDS ordering fence

    // store O into fragment-order Af[(grow>>4)*24 + kk*4+g][c=row&15][8]
    if (l31 < 24) {
        int d = h * 24 + l31;
        int grpA = (b * SS + qrA) >> 4;
        int grpB = (b * SS + qrB) >> 4;
        size_t fcol = (size_t)((d >> 5) * 4 + ((d >> 3) & 3)) * 128 + (d & 7);
        short* opA = Af + (size_t)grpA * 3072 + fcol;   // 3072 = 24*128
        short* opB = Af + (size_t)grpB * 3072 + fcol;
        #pragma unroll
        for (int r = 0; r < 16; r++) {
            int row = (r & 3) + 8 * (r >> 2) + 4 * hi;
            size_t off = (size_t)(r >> 3) * 3072 + (size_t)(row & 15) * 8;
            opA[off] = nb(accA[r] * llds[w][0][row]);
            opB[off] = nb(accB[r] * llds[w][1][row]);
        }
    }
}

// ---------------- final: out = attn(bf16) @ Wo + bo (Wo split hi+lo) ----------------
// blockIdx.y selects quarter of the 12 output n-tiles — 2048 blocks = 8/CU
__global__ __launch_bounds__(256) void final_kernel(
    const short* __restrict__ Af,
    const short* __restrict__ WoFh, const short* __restrict__ WoFl,
    const float* __restrict__ bo, float* __restrict__ out)
{
    int tid = threadIdx.x;
    int lane = tid & 63, w = tid >> 6;
    int c = lane & 15, g = lane >> 4;
    int r0 = blockIdx.x * 64 + w * 16;
    int n0 = blockIdx.y * 3;

    short8 a[6];
    #pragma unroll
    for (int kk = 0; kk < 6; kk++)
        a[kk] = *(const short8*)(Af + ((size_t)(r0 >> 4) * 24 + kk*4 + g) * 128 + c * 8);

    f32x4 acc[3];
    #pragma unroll
    for (int n = 0; n < 3; n++) acc[n] = (f32x4){0.f,0.f,0.f,0.f};

    #pragma unroll
    for (int kk = 0; kk < 6; kk++) {
        #pragma unroll
        for (int n = 0; n < 3; n++) {
            const short* bh_p = WoFh + (size_t)((n0+n)*6 + kk) * 512 + lane * 8;
            const short* bl_p = WoFl + (size_t)((n0+n)*6 + kk) * 512 + lane * 8;
            short8 bh = *(const short8*)bh_p;
            short8 bl = *(const short8*)bl_p;
            acc[n] = MFMA16(a[kk], bh, acc[n]);
            acc[n] = MFMA16(a[kk], bl, acc[n]);
        }
    }

    #pragma unroll
    for (int n = 0; n < 3; n++) {
        int col = (n0+n)*16 + c;
        float bv = bo[col];
        #pragma unroll
        for (int r = 0; r < 4; r++) {
            out[(size_t)(r0 + g*4 + r) * DD + col] = acc[n][r] + bv;
        }
    }
}

extern "C" void kernel_launch(void* const* d_in, const int* in_sizes, int n_in,
                              void* d_out, int out_size, void* d_ws, size_t ws_size,
                              hipStream_t stream)
{
    const float* x    = (const float*)d_in[0];
    const void*  mask = d_in[1];
    const float* Wq   = (const float*)d_in[2];
    const float* bq   = (const float*)d_in[3];
    const float* Wk   = (const float*)d_in[4];
    const float* bk   = (const float*)d_in[5];
    const float* Wv   = (const float*)d_in[6];
    const float* bv   = (const float*)d_in[7];
    const float* Wo   = (const float*)d_in[8];
    const float* bo   = (const float*)d_in[9];
    float* out = (float*)d_out;

    char* ws = (char*)d_ws;
    size_t off = 0;
    float* maskf = (float*)(ws + off); off += (size_t)BB*SS*4;          // 128 KB
    short* Q     = (short*)(ws + off); off += (size_t)BB*HH*SS*DHP*2;   // 16 MB
    short* KF    = (short*)(ws + off); off += (size_t)BB*HH*SS*DHP*2;   // 16 MB
    short* VF    = (short*)(ws + off); off += (size_t)BB*HH*SS*DHP*2;   // 16 MB
    short* Af    = (short*)(ws + off); off += (size_t)BB*SS*DD*2;       // 12 MB
    short* WqF   = (short*)(ws + off); off += (size_t)HH*DHP*DD*2;
    short* WkF   = (short*)(ws + off); off += (size_t)HH*DHP*DD*2;
    short* WvF   = (short*)(ws + off); off += (size_t)HH*DHP*DD*2;
    short* WoFh  = (short*)(ws + off); off += (size_t)DD*DD*2;
    short* WoFl  = (short*)(ws + off); off += (size_t)DD*DD*2;
    short* Vc    = (short*)(ws + off); off += (size_t)BB*HH*SS*DHP*2;   // 16 MB
    int*   inv   = (int*)  (ws + off); off += (size_t)BB*SS*4;          // 128 KB
    int*   cnt   = (int*)  (ws + off); off += 256;

    prep_kernel<<<dim3(720), dim3(256), 0, stream>>>(
        Wq, Wk, Wv, Wo, WqF, WkF, WvF, WoFh, WoFl);
    scan_kernel<<<dim3(BB), dim3(1024), 0, stream>>>(mask, maskf, inv, cnt);
    proj_kernel<<<dim3(512, 4), dim3(256), 0, stream>>>(
        x, bq, bk, bv, WqF, WkF, WvF, maskf, inv, Q, KF, Vc);
    vtrans_kernel<<<dim3(256, 4), dim3(256), 0, stream>>>(Vc, VF);
    flash_kernel<<<dim3(1024), dim3(256), 0, stream>>>(
        Q, KF, VF, cnt, Af);
    final_kernel<<<dim3(512, 4), dim3(256), 0, stream>>>(
        Af, WoFh, WoFl, bo, out);
}

// Round 14
// 102.246 us; speedup vs baseline: 1.0917x; 1.0917x over previous
//
#include <hip/hip_runtime.h>

typedef __attribute__((ext_vector_type(8))) short short8;
typedef __attribute__((ext_vector_type(4))) float f32x4;
typedef __attribute__((ext_vector_type(16))) float f32x16;
typedef __attribute__((ext_vector_type(2))) unsigned uint2v;
typedef __attribute__((ext_vector_type(4))) unsigned uint4v;

#define MFMA16(a,b,c) __builtin_amdgcn_mfma_f32_16x16x32_bf16((a),(b),(c),0,0,0)
#define MFMA32(a,b,c) __builtin_amdgcn_mfma_f32_32x32x16_bf16((a),(b),(c),0,0,0)

#define BB 32
#define SS 1024
#define DD 192
#define HH 8
#define DHP 32   // padded head dim (24 -> 32); col 31 = mask-bias, col 24 of V = ones

// Q pre-scale: log2(e) / sqrt(24)  -> exp2(S) == softmax numerator
#define SCALE_Q 0.294468266742895f

__device__ __forceinline__ short nb(float f) {
    __bf16 h = (__bf16)f;
    return __builtin_bit_cast(short, h);
}
__device__ __forceinline__ float bf2f(short s) {
    union { unsigned u; float f; } v; v.u = ((unsigned)(unsigned short)s) << 16;
    return v.f;
}
__device__ __forceinline__ unsigned pk2(float a, float b) {
    unsigned short lo = __builtin_bit_cast(unsigned short, (__bf16)a);
    unsigned short hi = __builtin_bit_cast(unsigned short, (__bf16)b);
    return (unsigned)lo | ((unsigned)hi << 16);
}

// ---------------- prep: fragment-order weight layouts ----------------
__global__ __launch_bounds__(256) void prep_kernel(
    const float* __restrict__ Wq, const float* __restrict__ Wk, const float* __restrict__ Wv,
    const float* __restrict__ Wo,
    short* __restrict__ WqF, short* __restrict__ WkF, short* __restrict__ WvF,
    short* __restrict__ WoFh, short* __restrict__ WoFl)
{
    int idx = blockIdx.x * 256 + threadIdx.x;
    const int NWX   = 3 * HH * DHP * DD;     // 147456
    const int NWO   = DD * DD;               // 36864
    if (idx < NWX) {
        int j = idx;
        int mat = j / (HH * DHP * DD);
        int jj  = j % (HH * DHP * DD);
        int h   = jj / (DHP * DD);
        int rem = jj % (DHP * DD);
        int e   = rem / DD;       // actual output col 0..31
        int d   = rem % DD;       // input dim
        const float* W = (mat == 0) ? Wq : (mat == 1) ? Wk : Wv;
        short* WF      = (mat == 0) ? WqF : (mat == 1) ? WkF : WvF;
        float val = (e < 24) ? W[(h * DD + d) * 24 + e] : 0.f;   // pad e>=24 with 0
        int nt = e & 1, cc = e >> 1;
        int kk = d >> 5, g = (d >> 3) & 3, ee = d & 7;
        WF[(size_t)((((h*2+nt)*6 + kk)*64) + g*16 + cc)*8 + ee] = nb(val);
    } else if (idx < NWX + NWO) {
        int j = idx - NWX;
        int n = j / DD, k = j % DD;    // n = out col, k = in dim
        float f = Wo[k * DD + n];
        short hi = nb(f);
        int nn = n >> 4, cc = n & 15;
        int kk = k >> 5, g = (k >> 3) & 3, ee = k & 7;
        size_t addr = (size_t)(((nn*6 + kk)*64) + g*16 + cc)*8 + ee;
        WoFh[addr] = hi;
        WoFl[addr] = nb(f - bf2f(hi));   // split-bf16 low part
    }
}

// ---------------- scan: mask normalize + per-batch compaction map ----------------
// fwd[b][pos] = original s (unmasked first 0..cnt-1, masked packed after; bijective)
__global__ __launch_bounds__(1024) void scan_kernel(
    const void* __restrict__ mask_raw,
    float* __restrict__ maskf, int* __restrict__ fwd, int* __restrict__ cnt)
{
    int b = blockIdx.x, t = threadIdx.x;
    int lane = t & 63, wv = t >> 6;
    int idx = b * SS + t;

    // dtype sniff: bool may arrive as int32 (0/1), float32 (0.0/1.0) or uint8
    const unsigned* mw = (const unsigned*)mask_raw;
    bool all01 = true, allf = true;
    #pragma unroll
    for (int i = 0; i < 16; i++) {
        unsigned w = mw[i];
        all01 = all01 && (w <= 1u);
        allf  = allf  && (w == 0u || w == 0x3F800000u);
    }
    bool m;
    if (all01)      m = (mw[idx] != 0u);
    else if (allf)  m = (((const float*)mask_raw)[idx] != 0.f);
    else            m = (((const unsigned char*)mask_raw)[idx] != 0);
    maskf[idx] = m ? 1.f : 0.f;

    unsigned long long bal = __ballot(m);
    int preU  = __popcll(bal & ((1ull << lane) - 1ull));
    int waveU = __popcll(bal);
    __shared__ int wsu[16];
    if (lane == 0) wsu[wv] = waveU;
    __syncthreads();
    int waveOffU = 0, totalU = 0;
    #pragma unroll
    for (int i = 0; i < 16; i++) {
        int v = wsu[i];
        if (i < wv) waveOffU += v;
        totalU += v;
    }
    int posU = waveOffU + preU;
    int posM = totalU + (wv * 64 - waveOffU) + (lane - preU);
    fwd[b * SS + (m ? posU : posM)] = t;
    if (t == 0) cnt[b] = totalU;
}

// ---------------- proj: Q/K/V = x @ W + b via MFMA, all NATURAL row order ----------------
// blockIdx.y = head-pair — 2048 blocks = 8/CU for latency hiding.
// Q[:,31] = 1.0; Kc[:,31] = mask ? 0 : -1e30; Vc[:,24] = 1.0 (denominator column)
__global__ __launch_bounds__(256) void proj_kernel(
    const float* __restrict__ x,
    const float* __restrict__ bq, const float* __restrict__ bk, const float* __restrict__ bv,
    const short* __restrict__ WqF, const short* __restrict__ WkF, const short* __restrict__ WvF,
    const float* __restrict__ maskf,
    short* __restrict__ Q, short* __restrict__ Kc, short* __restrict__ Vc)
{
    int tid = threadIdx.x;
    int lane = tid & 63, w = tid >> 6;
    int c = lane & 15, g = lane >> 4;
    int r0 = blockIdx.x * 64 + w * 16;
    int arow = r0 + c;
    int h0 = blockIdx.y * 2;

    int b_ = r0 >> 10;
    int s0 = (r0 & 1023) + g * 4;

    short8 a[6];
    #pragma unroll
    for (int kk = 0; kk < 6; kk++) {
        const float* px = x + (size_t)arow * DD + kk * 32 + g * 8;
        float4 f0 = *(const float4*)px;
        float4 f1 = *(const float4*)(px + 4);
        short8 t;
        t[0]=nb(f0.x); t[1]=nb(f0.y); t[2]=nb(f0.z); t[3]=nb(f0.w);
        t[4]=nb(f1.x); t[5]=nb(f1.y); t[6]=nb(f1.z); t[7]=nb(f1.w);
        a[kk] = t;
    }

    float mrow[4];
    #pragma unroll
    for (int r = 0; r < 4; r++) mrow[r] = maskf[b_ * SS + s0 + r];

    #pragma unroll
    for (int hh = 0; hh < 2; hh++) {
        int h = h0 + hh;
        int bh = b_ * HH + h;
        #pragma unroll
        for (int mat = 0; mat < 3; mat++) {
            const short* WF   = (mat==0)?WqF:(mat==1)?WkF:WvF;
            const float* bias = (mat==0)?bq:(mat==1)?bk:bv;

            f32x4 acc0 = {0.f,0.f,0.f,0.f};   // actual col 2c
            f32x4 acc1 = {0.f,0.f,0.f,0.f};   // actual col 2c+1
            const short* Wp0 = WF + (size_t)((h*2+0)*6) * 512 + lane * 8;
            const short* Wp1 = WF + (size_t)((h*2+1)*6) * 512 + lane * 8;
            #pragma unroll
            for (int kk = 0; kk < 6; kk++) {
                short8 b0 = *(const short8*)(Wp0 + kk * 512);
                short8 b1 = *(const short8*)(Wp1 + kk * 512);
                acc0 = MFMA16(a[kk], b0, acc0);
                acc1 = MFMA16(a[kk], b1, acc1);
            }
            float bv0 = 0.f, bv1 = 0.f;
            if (2*c < 24) {
                float2 bb = *(const float2*)(bias + h * 24 + 2 * c);
                bv0 = bb.x; bv1 = bb.y;
            }

            if (mat == 0) {
                #pragma unroll
                for (int r = 0; r < 4; r++) {
                    float v0 = (acc0[r] + bv0) * SCALE_Q;
                    float v1 = (c == 15) ? 1.0f : (acc1[r] + bv1) * SCALE_Q;
                    *(unsigned*)(Q + ((size_t)bh * SS + s0 + r) * DHP + 2*c) = pk2(v0, v1);
                }
            } else if (mat == 1) {
                #pragma unroll
                for (int r = 0; r < 4; r++) {
                    float v0 = acc0[r] + bv0;
                    float v1 = (c == 15) ? ((mrow[r] != 0.f) ? 0.f : -1e30f)
                                         : (acc1[r] + bv1);
                    *(unsigned*)(Kc + ((size_t)bh * SS + s0 + r) * DHP + 2*c) = pk2(v0, v1);
                }
            } else {
                #pragma unroll
                for (int r = 0; r < 4; r++) {
                    float v0 = (c == 12) ? 1.0f : (acc0[r] + bv0);  // col 24 = ones
                    float v1 = acc1[r] + bv1;
                    *(unsigned*)(Vc + ((size_t)bh * SS + s0 + r) * DHP + 2*c) = pk2(v0, v1);
                }
            }
        }
    }
}

// ---------------- kvprep: gather compacted rows, emit KF/VF fragment-tile layouts ----------------
// KF element (kpos,e): tile=kpos>>5, instr=e>>4, lane=((e>>3)&1)*32+(kpos&31), j=e&7
// VF element (kpos,e): tile=kpos>>5, instr=(kpos>>4)&1, lane=((kpos>>3)&1)*32+e, j=kpos&7
// block = (bh, 128-row quarter); skips quarters past the needed nt tiles
__global__ __launch_bounds__(256) void kvprep_kernel(
    const short* __restrict__ Kc, const short* __restrict__ Vc,
    const int* __restrict__ fwd, const int* __restrict__ cnt,
    short* __restrict__ KF, short* __restrict__ VF)
{
    int bh = blockIdx.x, c4 = blockIdx.y;
    int b = bh >> 3;
    int nt32 = ((cnt[b] + 31) >> 5) << 5;
    int row0 = c4 * 128;
    if (row0 >= nt32) return;

    __shared__ short lds[128][40];   // 80B row pitch (16B-aligned)
    int t = threadIdx.x;
    int srow[2];

    // ---- K stage: gather 128 rows (4 lanes x 16B per row) ----
    #pragma unroll
    for (int p = 0; p < 2; p++) {
        int j = p * 64 + (t >> 2);
        int part = t & 3;
        int s = fwd[b * SS + row0 + j];
        srow[p] = s;
        *(short8*)&lds[j][part * 8] =
            *(const short8*)(Kc + ((size_t)bh * SS + s) * DHP + part * 8);
    }
    __syncthreads();

    int tile_l = t >> 6, L = t & 63, l31 = L & 31, hi = L >> 5;
    short* kf0 = KF + (size_t)bh * SS * DHP + (size_t)(row0 / 32 + tile_l) * 1024;
    #pragma unroll
    for (int i = 0; i < 2; i++) {
        short8 o = *(const short8*)&lds[tile_l * 32 + l31][i * 16 + hi * 8];
        *(short8*)(kf0 + i * 512 + (size_t)L * 8) = o;
    }
    __syncthreads();

    // ---- V stage: same rows ----
    #pragma unroll
    for (int p = 0; p < 2; p++) {
        int j = p * 64 + (t >> 2);
        int part = t & 3;
        *(short8*)&lds[j][part * 8] =
            *(const short8*)(Vc + ((size_t)bh * SS + srow[p]) * DHP + part * 8);
    }
    __syncthreads();

    short* vf0 = VF + (size_t)bh * SS * DHP + (size_t)(row0 / 32 + tile_l) * 1024;
    #pragma unroll
    for (int i = 0; i < 2; i++) {
        short8 o;
        #pragma unroll
        for (int j2 = 0; j2 < 8; j2++)
            o[j2] = lds[tile_l * 32 + i * 16 + hi * 8 + j2][l31];
        *(short8*)(vf0 + i * 512 + (size_t)L * 8) = o;
    }
}

// ---------------- flash attention (swapped QK^T, in-register softmax) ----------------
__device__ __forceinline__ void fproc(const f32x16& S, f32x16& acc,
                                      short8 v0, short8 v1)
{
    float p[16];
    #pragma unroll
    for (int r = 0; r < 16; r++) p[r] = __builtin_amdgcn_exp2f(S[r]);

    unsigned c01 = pk2(p[0],  p[1]);
    unsigned c23 = pk2(p[2],  p[3]);
    unsigned c45 = pk2(p[4],  p[5]);
    unsigned c67 = pk2(p[6],  p[7]);
    unsigned c89 = pk2(p[8],  p[9]);
    unsigned cab = pk2(p[10], p[11]);
    unsigned ccd = pk2(p[12], p[13]);
    unsigned cef = pk2(p[14], p[15]);

    // permlane32_swap(a,b): x[l] = l<32 ? a[l] : b[l-32]
    //                       y[l] = l<32 ? a[l+32] : b[l]
    uint2v s0 = __builtin_amdgcn_permlane32_swap(c01, c45, false, false);
    uint2v s1 = __builtin_amdgcn_permlane32_swap(c23, c67, false, false);
    uint2v s2 = __builtin_amdgcn_permlane32_swap(c89, ccd, false, false);
    uint2v s3 = __builtin_amdgcn_permlane32_swap(cab, cef, false, false);

    uint4v w0v = { s0.x, s1.x, s0.y, s1.y };   // PV A-frag, kpos tile 0..15
    uint4v w1v = { s2.x, s3.x, s2.y, s3.y };   // kpos tile 16..31
    short8 pa0 = __builtin_bit_cast(short8, w0v);
    short8 pa1 = __builtin_bit_cast(short8, w1v);

    acc = MFMA32(pa0, v0, acc);
    acc = MFMA32(pa1, v1, acc);
}

// grid 512 = 256 bh x 2 qb; 4 q-chunks per wave (ILP-4 per K/V load)
__global__ __launch_bounds__(256, 2) void flash_kernel(
    const short* __restrict__ Q, const short* __restrict__ KF, const short* __restrict__ VF,
    const int* __restrict__ cnt, short* __restrict__ Af)
{
    __shared__ float llds[4][4][32];

    int idx = blockIdx.x;
    int bh = idx & 255;
    int qb = idx >> 8;          // 0..1
    int b = bh >> 3, h = bh & 7;

    int tid = threadIdx.x;
    int lane = tid & 63, w = tid >> 6;
    int l31 = lane & 31;
    int hi = lane >> 5;

    int nt = (cnt[b] + 31) >> 5;   // only tiles containing unmasked positions

    int qr0 = qb * 512 + w * 32;   // chunks at qr0 + cc*128

    short8 qf[4][2];
    #pragma unroll
    for (int cc = 0; cc < 4; cc++) {
        const short* Qp = Q + ((size_t)bh * SS + qr0 + cc * 128 + l31) * DHP + hi * 8;
        qf[cc][0] = *(const short8*)Qp;
        qf[cc][1] = *(const short8*)(Qp + 16);
    }

    const short* Kp = KF + (size_t)bh * SS * DHP + (size_t)lane * 8;
    const short* Vp = VF + (size_t)bh * SS * DHP + (size_t)lane * 8;

    f32x16 acc[4], Z16;
    #pragma unroll
    for (int r = 0; r < 16; r++) {
        acc[0][r] = 0.f; acc[1][r] = 0.f; acc[2][r] = 0.f; acc[3][r] = 0.f;
        Z16[r] = 0.f;
    }

    // prologue: load tile 0
    short8 k0 = *(const short8*)(Kp);
    short8 k1 = *(const short8*)(Kp + 512);
    short8 v0 = *(const short8*)(Vp);
    short8 v1 = *(const short8*)(Vp + 512);

    for (int kt = 0; kt < nt; kt++) {
        Kp += 1024;
        Vp += 1024;
        short8 nk0 = *(const short8*)(Kp);
        short8 nk1 = *(const short8*)(Kp + 512);
        short8 nv0 = *(const short8*)(Vp);
        short8 nv1 = *(const short8*)(Vp + 512);

        #pragma unroll
        for (int cc = 0; cc < 4; cc++) {
            f32x16 S = MFMA32(k0, qf[cc][0], Z16);
            S = MFMA32(k1, qf[cc][1], S);   // includes mask bias via channel e=31
            fproc(S, acc[cc], v0, v1);
        }

        k0 = nk0; k1 = nk1; v0 = nv0; v1 = nv1;
    }

    // denominator via V's ones-column: acc col 24 (lanes l31==24)
    if (l31 == 24) {
        #pragma unroll
        for (int cc = 0; cc < 4; cc++) {
            #pragma unroll
            for (int r = 0; r < 16; r++) {
                int row = (r & 3) + 8 * (r >> 2) + 4 * hi;
                llds[w][cc][row] = __builtin_amdgcn_rcpf(acc[cc][r]);
            }
        }
    }
    __builtin_amdgcn_wave_barrier();   // same-wave LDS ordering fence

    // store O into fragment-order Af[(grow>>4)*24 + kk*4+g][c=row&15][8]
    if (l31 < 24) {
        int d = h * 24 + l31;
        size_t fcol = (size_t)((d >> 5) * 4 + ((d >> 3) & 3)) * 128 + (d & 7);
        #pragma unroll
        for (int cc = 0; cc < 4; cc++) {
            int grp = (b * SS + qr0 + cc * 128) >> 4;
            short* op = Af + (size_t)grp * 3072 + fcol;   // 3072 = 24*128
            #pragma unroll
            for (int r = 0; r < 16; r++) {
                int row = (r & 3) + 8 * (r >> 2) + 4 * hi;
                size_t off = (size_t)(r >> 3) * 3072 + (size_t)(row & 15) * 8;
                op[off] = nb(acc[cc][r] * llds[w][cc][row]);
            }
        }
    }
}

// ---------------- final: out = attn(bf16) @ Wo + bo (Wo split hi+lo) ----------------
// blockIdx.y selects quarter of the 12 output n-tiles — 2048 blocks = 8/CU
__global__ __launch_bounds__(256) void final_kernel(
    const short* __restrict__ Af,
    const short* __restrict__ WoFh, const short* __restrict__ WoFl,
    const float* __restrict__ bo, float* __restrict__ out)
{
    int tid = threadIdx.x;
    int lane = tid & 63, w = tid >> 6;
    int c = lane & 15, g = lane >> 4;
    int r0 = blockIdx.x * 64 + w * 16;
    int n0 = blockIdx.y * 3;

    short8 a[6];
    #pragma unroll
    for (int kk = 0; kk < 6; kk++)
        a[kk] = *(const short8*)(Af + ((size_t)(r0 >> 4) * 24 + kk*4 + g) * 128 + c * 8);

    f32x4 acc[3];
    #pragma unroll
    for (int n = 0; n < 3; n++) acc[n] = (f32x4){0.f,0.f,0.f,0.f};

    #pragma unroll
    for (int kk = 0; kk < 6; kk++) {
        #pragma unroll
        for (int n = 0; n < 3; n++) {
            const short* bh_p = WoFh + (size_t)((n0+n)*6 + kk) * 512 + lane * 8;
            const short* bl_p = WoFl + (size_t)((n0+n)*6 + kk) * 512 + lane * 8;
            short8 bh = *(const short8*)bh_p;
            short8 bl = *(const short8*)bl_p;
            acc[n] = MFMA16(a[kk], bh, acc[n]);
            acc[n] = MFMA16(a[kk], bl, acc[n]);
        }
    }

    #pragma unroll
    for (int n = 0; n < 3; n++) {
        int col = (n0+n)*16 + c;
        float bv = bo[col];
        #pragma unroll
        for (int r = 0; r < 4; r++) {
            out[(size_t)(r0 + g*4 + r) * DD + col] = acc[n][r] + bv;
        }
    }
}

extern "C" void kernel_launch(void* const* d_in, const int* in_sizes, int n_in,
                              void* d_out, int out_size, void* d_ws, size_t ws_size,
                              hipStream_t stream)
{
    const float* x    = (const float*)d_in[0];
    const void*  mask = d_in[1];
    const float* Wq   = (const float*)d_in[2];
    const float* bq   = (const float*)d_in[3];
    const float* Wk   = (const float*)d_in[4];
    const float* bk   = (const float*)d_in[5];
    const float* Wv   = (const float*)d_in[6];
    const float* bv   = (const float*)d_in[7];
    const float* Wo   = (const float*)d_in[8];
    const float* bo   = (const float*)d_in[9];
    float* out = (float*)d_out;

    char* ws = (char*)d_ws;
    size_t off = 0;
    float* maskf = (float*)(ws + off); off += (size_t)BB*SS*4;          // 128 KB
    short* Q     = (short*)(ws + off); off += (size_t)BB*HH*SS*DHP*2;   // 16 MB
    short* Kc    = (short*)(ws + off); off += (size_t)BB*HH*SS*DHP*2;   // 16 MB (Af aliases)
    short* Vc    = (short*)(ws + off); off += (size_t)BB*HH*SS*DHP*2;   // 16 MB
    short* KF    = (short*)(ws + off); off += (size_t)BB*HH*SS*DHP*2;   // 16 MB
    short* VF    = (short*)(ws + off); off += (size_t)BB*HH*SS*DHP*2;   // 16 MB
    short* WqF   = (short*)(ws + off); off += (size_t)HH*DHP*DD*2;
    short* WkF   = (short*)(ws + off); off += (size_t)HH*DHP*DD*2;
    short* WvF   = (short*)(ws + off); off += (size_t)HH*DHP*DD*2;
    short* WoFh  = (short*)(ws + off); off += (size_t)DD*DD*2;
    short* WoFl  = (short*)(ws + off); off += (size_t)DD*DD*2;
    int*   fwd   = (int*)  (ws + off); off += (size_t)BB*SS*4;          // 128 KB
    int*   cnt   = (int*)  (ws + off); off += 256;

    // Af (12 MB) aliases Kc (16 MB): Kc is dead after kvprep, Af written by flash
    short* Af = Kc;

    prep_kernel<<<dim3(720), dim3(256), 0, stream>>>(
        Wq, Wk, Wv, Wo, WqF, WkF, WvF, WoFh, WoFl);
    scan_kernel<<<dim3(BB), dim3(1024), 0, stream>>>(mask, maskf, fwd, cnt);
    proj_kernel<<<dim3(512, 4), dim3(256), 0, stream>>>(
        x, bq, bk, bv, WqF, WkF, WvF, maskf, Q, Kc, Vc);
    kvprep_kernel<<<dim3(256, 8), dim3(256), 0, stream>>>(
        Kc, Vc, fwd, cnt, KF, VF);
    flash_kernel<<<dim3(512), dim3(256), 0, stream>>>(
        Q, KF, VF, cnt, Af);
    final_kernel<<<dim3(512, 4), dim3(256), 0, stream>>>(
        Af, WoFh, WoFl, bo, out);
}

// Round 15
// 100.835 us; speedup vs baseline: 1.1069x; 1.0140x over previous
//
#include <hip/hip_runtime.h>

typedef __attribute__((ext_vector_type(8))) short short8;
typedef __attribute__((ext_vector_type(4))) float f32x4;
typedef __attribute__((ext_vector_type(16))) float f32x16;
typedef __attribute__((ext_vector_type(2))) unsigned uint2v;
typedef __attribute__((ext_vector_type(4))) unsigned uint4v;

#define MFMA16(a,b,c) __builtin_amdgcn_mfma_f32_16x16x32_bf16((a),(b),(c),0,0,0)
#define MFMA32(a,b,c) __builtin_amdgcn_mfma_f32_32x32x16_bf16((a),(b),(c),0,0,0)

#define BB 32
#define SS 1024
#define DD 192
#define HH 8
#define DHP 32   // padded head dim (24 -> 32); col 31 = mask-bias, col 24 of V = ones

// Q pre-scale: log2(e) / sqrt(24)  -> exp2(S) == softmax numerator
#define SCALE_Q 0.294468266742895f

__device__ __forceinline__ short nb(float f) {
    __bf16 h = (__bf16)f;
    return __builtin_bit_cast(short, h);
}
__device__ __forceinline__ float bf2f(short s) {
    union { unsigned u; float f; } v; v.u = ((unsigned)(unsigned short)s) << 16;
    return v.f;
}
__device__ __forceinline__ unsigned pk2(float a, float b) {
    unsigned short lo = __builtin_bit_cast(unsigned short, (__bf16)a);
    unsigned short hi = __builtin_bit_cast(unsigned short, (__bf16)b);
    return (unsigned)lo | ((unsigned)hi << 16);
}

// ---------------- prep: fragment-order weight layouts ----------------
__global__ __launch_bounds__(256) void prep_kernel(
    const float* __restrict__ Wq, const float* __restrict__ Wk, const float* __restrict__ Wv,
    const float* __restrict__ Wo,
    short* __restrict__ WqF, short* __restrict__ WkF, short* __restrict__ WvF,
    short* __restrict__ WoFh, short* __restrict__ WoFl)
{
    int idx = blockIdx.x * 256 + threadIdx.x;
    const int NWX   = 3 * HH * DHP * DD;     // 147456
    const int NWO   = DD * DD;               // 36864
    if (idx < NWX) {
        int j = idx;
        int mat = j / (HH * DHP * DD);
        int jj  = j % (HH * DHP * DD);
        int h   = jj / (DHP * DD);
        int rem = jj % (DHP * DD);
        int e   = rem / DD;       // actual output col 0..31
        int d   = rem % DD;       // input dim
        const float* W = (mat == 0) ? Wq : (mat == 1) ? Wk : Wv;
        short* WF      = (mat == 0) ? WqF : (mat == 1) ? WkF : WvF;
        float val = (e < 24) ? W[(h * DD + d) * 24 + e] : 0.f;   // pad e>=24 with 0
        int nt = e & 1, cc = e >> 1;
        int kk = d >> 5, g = (d >> 3) & 3, ee = d & 7;
        WF[(size_t)((((h*2+nt)*6 + kk)*64) + g*16 + cc)*8 + ee] = nb(val);
    } else if (idx < NWX + NWO) {
        int j = idx - NWX;
        int n = j / DD, k = j % DD;    // n = out col, k = in dim
        float f = Wo[k * DD + n];
        short hi = nb(f);
        int nn = n >> 4, cc = n & 15;
        int kk = k >> 5, g = (k >> 3) & 3, ee = k & 7;
        size_t addr = (size_t)(((nn*6 + kk)*64) + g*16 + cc)*8 + ee;
        WoFh[addr] = hi;
        WoFl[addr] = nb(f - bf2f(hi));   // split-bf16 low part
    }
}

// ---------------- xprep: x (f32) -> xF bf16 A-fragment order ----------------
// xF[(row>>4)*6 + kk][lane=g*16+c][8] : element = x[(row16*16)+c][kk*32+g*8+j]
__global__ __launch_bounds__(256) void xprep_kernel(
    const float* __restrict__ x, short* __restrict__ xF)
{
    __shared__ short lds[64][200];   // 400B pitch: 16B-aligned, 2-way bank alias (free)
    int t = threadIdx.x;
    int r0 = blockIdx.x * 64;

    // load 64 rows x 192 f32, fully coalesced (3072 float4s / 256 threads = 12 each)
    #pragma unroll
    for (int i = 0; i < 12; i++) {
        int idx = i * 256 + t;
        int row = idx / 48;              // 48 float4 per row
        int colf = (idx % 48) * 4;
        float4 f = *(const float4*)(x + ((size_t)(r0 + row)) * DD + colf);
        lds[row][colf + 0] = nb(f.x);
        lds[row][colf + 1] = nb(f.y);
        lds[row][colf + 2] = nb(f.z);
        lds[row][colf + 3] = nb(f.w);
    }
    __syncthreads();

    int w = t >> 6, lane = t & 63, c = lane & 15, g = lane >> 4;
    int br = blockIdx.x * 4 + w;        // 16-row fragment block
    short* outb = xF + (size_t)br * 6 * 512;
    #pragma unroll
    for (int kk = 0; kk < 6; kk++) {
        short8 o = *(const short8*)&lds[w * 16 + c][kk * 32 + g * 8];
        *(short8*)(outb + kk * 512 + (size_t)lane * 8) = o;
    }
}

// ---------------- scan: mask normalize + per-batch compaction map ----------------
// fwd[b][pos] = original s (unmasked first 0..cnt-1, masked packed after; bijective)
__global__ __launch_bounds__(1024) void scan_kernel(
    const void* __restrict__ mask_raw,
    float* __restrict__ maskf, int* __restrict__ fwd, int* __restrict__ cnt)
{
    int b = blockIdx.x, t = threadIdx.x;
    int lane = t & 63, wv = t >> 6;
    int idx = b * SS + t;

    // dtype sniff: bool may arrive as int32 (0/1), float32 (0.0/1.0) or uint8
    const unsigned* mw = (const unsigned*)mask_raw;
    bool all01 = true, allf = true;
    #pragma unroll
    for (int i = 0; i < 16; i++) {
        unsigned w = mw[i];
        all01 = all01 && (w <= 1u);
        allf  = allf  && (w == 0u || w == 0x3F800000u);
    }
    bool m;
    if (all01)      m = (mw[idx] != 0u);
    else if (allf)  m = (((const float*)mask_raw)[idx] != 0.f);
    else            m = (((const unsigned char*)mask_raw)[idx] != 0);
    maskf[idx] = m ? 1.f : 0.f;

    unsigned long long bal = __ballot(m);
    int preU  = __popcll(bal & ((1ull << lane) - 1ull));
    int waveU = __popcll(bal);
    __shared__ int wsu[16];
    if (lane == 0) wsu[wv] = waveU;
    __syncthreads();
    int waveOffU = 0, totalU = 0;
    #pragma unroll
    for (int i = 0; i < 16; i++) {
        int v = wsu[i];
        if (i < wv) waveOffU += v;
        totalU += v;
    }
    int posU = waveOffU + preU;
    int posM = totalU + (wv * 64 - waveOffU) + (lane - preU);
    fwd[b * SS + (m ? posU : posM)] = t;
    if (t == 0) cnt[b] = totalU;
}

// ---------------- proj: Q/K/V = xF @ W + b via MFMA, all NATURAL row order ----------------
// blockIdx.y = head-pair — 2048 blocks = 8/CU for latency hiding.
// Q[:,31] = 1.0; Kc[:,31] = mask ? 0 : -1e30; Vc[:,24] = 1.0 (denominator column)
__global__ __launch_bounds__(256) void proj_kernel(
    const short* __restrict__ xF,
    const float* __restrict__ bq, const float* __restrict__ bk, const float* __restrict__ bv,
    const short* __restrict__ WqF, const short* __restrict__ WkF, const short* __restrict__ WvF,
    const float* __restrict__ maskf,
    short* __restrict__ Q, short* __restrict__ Kc, short* __restrict__ Vc)
{
    int tid = threadIdx.x;
    int lane = tid & 63, w = tid >> 6;
    int c = lane & 15, g = lane >> 4;
    int r0 = blockIdx.x * 64 + w * 16;
    int h0 = blockIdx.y * 2;

    int b_ = r0 >> 10;
    int s0 = (r0 & 1023) + g * 4;

    // A-fragments: coalesced lane*16B loads from fragment-ordered xF
    short8 a[6];
    const short* xfb = xF + (size_t)(r0 >> 4) * 6 * 512 + (size_t)lane * 8;
    #pragma unroll
    for (int kk = 0; kk < 6; kk++)
        a[kk] = *(const short8*)(xfb + kk * 512);

    float mrow[4];
    #pragma unroll
    for (int r = 0; r < 4; r++) mrow[r] = maskf[b_ * SS + s0 + r];

    #pragma unroll
    for (int hh = 0; hh < 2; hh++) {
        int h = h0 + hh;
        int bh = b_ * HH + h;
        #pragma unroll
        for (int mat = 0; mat < 3; mat++) {
            const short* WF   = (mat==0)?WqF:(mat==1)?WkF:WvF;
            const float* bias = (mat==0)?bq:(mat==1)?bk:bv;

            f32x4 acc0 = {0.f,0.f,0.f,0.f};   // actual col 2c
            f32x4 acc1 = {0.f,0.f,0.f,0.f};   // actual col 2c+1
            const short* Wp0 = WF + (size_t)((h*2+0)*6) * 512 + lane * 8;
            const short* Wp1 = WF + (size_t)((h*2+1)*6) * 512 + lane * 8;
            #pragma unroll
            for (int kk = 0; kk < 6; kk++) {
                short8 b0 = *(const short8*)(Wp0 + kk * 512);
                short8 b1 = *(const short8*)(Wp1 + kk * 512);
                acc0 = MFMA16(a[kk], b0, acc0);
                acc1 = MFMA16(a[kk], b1, acc1);
            }
            float bv0 = 0.f, bv1 = 0.f;
            if (2*c < 24) {
                float2 bb = *(const float2*)(bias + h * 24 + 2 * c);
                bv0 = bb.x; bv1 = bb.y;
            }

            if (mat == 0) {
                #pragma unroll
                for (int r = 0; r < 4; r++) {
                    float v0 = (acc0[r] + bv0) * SCALE_Q;
                    float v1 = (c == 15) ? 1.0f : (acc1[r] + bv1) * SCALE_Q;
                    *(unsigned*)(Q + ((size_t)bh * SS + s0 + r) * DHP + 2*c) = pk2(v0, v1);
                }
            } else if (mat == 1) {
                #pragma unroll
                for (int r = 0; r < 4; r++) {
                    float v0 = acc0[r] + bv0;
                    float v1 = (c == 15) ? ((mrow[r] != 0.f) ? 0.f : -1e30f)
                                         : (acc1[r] + bv1);
                    *(unsigned*)(Kc + ((size_t)bh * SS + s0 + r) * DHP + 2*c) = pk2(v0, v1);
                }
            } else {
                #pragma unroll
                for (int r = 0; r < 4; r++) {
                    float v0 = (c == 12) ? 1.0f : (acc0[r] + bv0);  // col 24 = ones
                    float v1 = acc1[r] + bv1;
                    *(unsigned*)(Vc + ((size_t)bh * SS + s0 + r) * DHP + 2*c) = pk2(v0, v1);
                }
            }
        }
    }
}

// ---------------- kvprep: gather compacted rows, emit KF/VF fragment-tile layouts ----------------
// KF element (kpos,e): tile=kpos>>5, instr=e>>4, lane=((e>>3)&1)*32+(kpos&31), j=e&7
// VF element (kpos,e): tile=kpos>>5, instr=(kpos>>4)&1, lane=((kpos>>3)&1)*32+e, j=kpos&7
// block = (bh, 128-row quarter); skips quarters past the needed nt tiles
__global__ __launch_bounds__(256) void kvprep_kernel(
    const short* __restrict__ Kc, const short* __restrict__ Vc,
    const int* __restrict__ fwd, const int* __restrict__ cnt,
    short* __restrict__ KF, short* __restrict__ VF)
{
    int bh = blockIdx.x, c4 = blockIdx.y;
    int b = bh >> 3;
    int nt32 = ((cnt[b] + 31) >> 5) << 5;
    int row0 = c4 * 128;
    if (row0 >= nt32) return;

    __shared__ short lds[128][40];   // 80B row pitch (16B-aligned)
    int t = threadIdx.x;
    int srow[2];

    // ---- K stage: gather 128 rows (4 lanes x 16B per row) ----
    #pragma unroll
    for (int p = 0; p < 2; p++) {
        int j = p * 64 + (t >> 2);
        int part = t & 3;
        int s = fwd[b * SS + row0 + j];
        srow[p] = s;
        *(short8*)&lds[j][part * 8] =
            *(const short8*)(Kc + ((size_t)bh * SS + s) * DHP + part * 8);
    }
    __syncthreads();

    int tile_l = t >> 6, L = t & 63, l31 = L & 31, hi = L >> 5;
    short* kf0 = KF + (size_t)bh * SS * DHP + (size_t)(row0 / 32 + tile_l) * 1024;
    #pragma unroll
    for (int i = 0; i < 2; i++) {
        short8 o = *(const short8*)&lds[tile_l * 32 + l31][i * 16 + hi * 8];
        *(short8*)(kf0 + i * 512 + (size_t)L * 8) = o;
    }
    __syncthreads();

    // ---- V stage: same rows ----
    #pragma unroll
    for (int p = 0; p < 2; p++) {
        int j = p * 64 + (t >> 2);
        int part = t & 3;
        *(short8*)&lds[j][part * 8] =
            *(const short8*)(Vc + ((size_t)bh * SS + srow[p]) * DHP + part * 8);
    }
    __syncthreads();

    short* vf0 = VF + (size_t)bh * SS * DHP + (size_t)(row0 / 32 + tile_l) * 1024;
    #pragma unroll
    for (int i = 0; i < 2; i++) {
        short8 o;
        #pragma unroll
        for (int j2 = 0; j2 < 8; j2++)
            o[j2] = lds[tile_l * 32 + i * 16 + hi * 8 + j2][l31];
        *(short8*)(vf0 + i * 512 + (size_t)L * 8) = o;
    }
}

// ---------------- flash attention (swapped QK^T, in-register softmax) ----------------
__device__ __forceinline__ void fproc(const f32x16& S, f32x16& acc,
                                      short8 v0, short8 v1)
{
    float p[16];
    #pragma unroll
    for (int r = 0; r < 16; r++) p[r] = __builtin_amdgcn_exp2f(S[r]);

    unsigned c01 = pk2(p[0],  p[1]);
    unsigned c23 = pk2(p[2],  p[3]);
    unsigned c45 = pk2(p[4],  p[5]);
    unsigned c67 = pk2(p[6],  p[7]);
    unsigned c89 = pk2(p[8],  p[9]);
    unsigned cab = pk2(p[10], p[11]);
    unsigned ccd = pk2(p[12], p[13]);
    unsigned cef = pk2(p[14], p[15]);

    // permlane32_swap(a,b): x[l] = l<32 ? a[l] : b[l-32]
    //                       y[l] = l<32 ? a[l+32] : b[l]
    uint2v s0 = __builtin_amdgcn_permlane32_swap(c01, c45, false, false);
    uint2v s1 = __builtin_amdgcn_permlane32_swap(c23, c67, false, false);
    uint2v s2 = __builtin_amdgcn_permlane32_swap(c89, ccd, false, false);
    uint2v s3 = __builtin_amdgcn_permlane32_swap(cab, cef, false, false);

    uint4v w0v = { s0.x, s1.x, s0.y, s1.y };   // PV A-frag, kpos tile 0..15
    uint4v w1v = { s2.x, s3.x, s2.y, s3.y };   // kpos tile 16..31
    short8 pa0 = __builtin_bit_cast(short8, w0v);
    short8 pa1 = __builtin_bit_cast(short8, w1v);

    acc = MFMA32(pa0, v0, acc);
    acc = MFMA32(pa1, v1, acc);
}

// grid 512 = 256 bh x 2 qb; 4 q-chunks per wave (ILP-4 per K/V load)
__global__ __launch_bounds__(256, 2) void flash_kernel(
    const short* __restrict__ Q, const short* __restrict__ KF, const short* __restrict__ VF,
    const int* __restrict__ cnt, short* __restrict__ Af)
{
    __shared__ float llds[4][4][32];

    int idx = blockIdx.x;
    int bh = idx & 255;
    int qb = idx >> 8;          // 0..1
    int b = bh >> 3, h = bh & 7;

    int tid = threadIdx.x;
    int lane = tid & 63, w = tid >> 6;
    int l31 = lane & 31;
    int hi = lane >> 5;

    int nt = (cnt[b] + 31) >> 5;   // only tiles containing unmasked positions

    int qr0 = qb * 512 + w * 32;   // chunks at qr0 + cc*128

    short8 qf[4][2];
    #pragma unroll
    for (int cc = 0; cc < 4; cc++) {
        const short* Qp = Q + ((size_t)bh * SS + qr0 + cc * 128 + l31) * DHP + hi * 8;
        qf[cc][0] = *(const short8*)Qp;
        qf[cc][1] = *(const short8*)(Qp + 16);
    }

    const short* Kp = KF + (size_t)bh * SS * DHP + (size_t)lane * 8;
    const short* Vp = VF + (size_t)bh * SS * DHP + (size_t)lane * 8;

    f32x16 acc[4], Z16;
    #pragma unroll
    for (int r = 0; r < 16; r++) {
        acc[0][r] = 0.f; acc[1][r] = 0.f; acc[2][r] = 0.f; acc[3][r] = 0.f;
        Z16[r] = 0.f;
    }

    // prologue: load tile 0
    short8 k0 = *(const short8*)(Kp);
    short8 k1 = *(const short8*)(Kp + 512);
    short8 v0 = *(const short8*)(Vp);
    short8 v1 = *(const short8*)(Vp + 512);

    for (int kt = 0; kt < nt; kt++) {
        Kp += 1024;
        Vp += 1024;
        short8 nk0 = *(const short8*)(Kp);
        short8 nk1 = *(const short8*)(Kp + 512);
        short8 nv0 = *(const short8*)(Vp);
        short8 nv1 = *(const short8*)(Vp + 512);

        #pragma unroll
        for (int cc = 0; cc < 4; cc++) {
            f32x16 S = MFMA32(k0, qf[cc][0], Z16);
            S = MFMA32(k1, qf[cc][1], S);   // includes mask bias via channel e=31
            fproc(S, acc[cc], v0, v1);
        }

        k0 = nk0; k1 = nk1; v0 = nv0; v1 = nv1;
    }

    // denominator via V's ones-column: acc col 24 (lanes l31==24)
    if (l31 == 24) {
        #pragma unroll
        for (int cc = 0; cc < 4; cc++) {
            #pragma unroll
            for (int r = 0; r < 16; r++) {
                int row = (r & 3) + 8 * (r >> 2) + 4 * hi;
                llds[w][cc][row] = __builtin_amdgcn_rcpf(acc[cc][r]);
            }
        }
    }
    __builtin_amdgcn_wave_barrier();   // same-wave LDS ordering fence

    // store O into fragment-order Af[(grow>>4)*24 + kk*4+g][c=row&15][8]
    if (l31 < 24) {
        int d = h * 24 + l31;
        size_t fcol = (size_t)((d >> 5) * 4 + ((d >> 3) & 3)) * 128 + (d & 7);
        #pragma unroll
        for (int cc = 0; cc < 4; cc++) {
            int grp = (b * SS + qr0 + cc * 128) >> 4;
            short* op = Af + (size_t)grp * 3072 + fcol;   // 3072 = 24*128
            #pragma unroll
            for (int r = 0; r < 16; r++) {
                int row = (r & 3) + 8 * (r >> 2) + 4 * hi;
                size_t off = (size_t)(r >> 3) * 3072 + (size_t)(row & 15) * 8;
                op[off] = nb(acc[cc][r] * llds[w][cc][row]);
            }
        }
    }
}

// ---------------- final: out = attn(bf16) @ Wo + bo (Wo split hi+lo) ----------------
// blockIdx.y selects quarter of the 12 output n-tiles — 2048 blocks = 8/CU
__global__ __launch_bounds__(256) void final_kernel(
    const short* __restrict__ Af,
    const short* __restrict__ WoFh, const short* __restrict__ WoFl,
    const float* __restrict__ bo, float* __restrict__ out)
{
    int tid = threadIdx.x;
    int lane = tid & 63, w = tid >> 6;
    int c = lane & 15, g = lane >> 4;
    int r0 = blockIdx.x * 64 + w * 16;
    int n0 = blockIdx.y * 3;

    short8 a[6];
    #pragma unroll
    for (int kk = 0; kk < 6; kk++)
        a[kk] = *(const short8*)(Af + ((size_t)(r0 >> 4) * 24 + kk*4 + g) * 128 + c * 8);

    f32x4 acc[3];
    #pragma unroll
    for (int n = 0; n < 3; n++) acc[n] = (f32x4){0.f,0.f,0.f,0.f};

    #pragma unroll
    for (int kk = 0; kk < 6; kk++) {
        #pragma unroll
        for (int n = 0; n < 3; n++) {
            const short* bh_p = WoFh + (size_t)((n0+n)*6 + kk) * 512 + lane * 8;
            const short* bl_p = WoFl + (size_t)((n0+n)*6 + kk) * 512 + lane * 8;
            short8 bh = *(const short8*)bh_p;
            short8 bl = *(const short8*)bl_p;
            acc[n] = MFMA16(a[kk], bh, acc[n]);
            acc[n] = MFMA16(a[kk], bl, acc[n]);
        }
    }

    #pragma unroll
    for (int n = 0; n < 3; n++) {
        int col = (n0+n)*16 + c;
        float bv = bo[col];
        #pragma unroll
        for (int r = 0; r < 4; r++) {
            out[(size_t)(r0 + g*4 + r) * DD + col] = acc[n][r] + bv;
        }
    }
}

extern "C" void kernel_launch(void* const* d_in, const int* in_sizes, int n_in,
                              void* d_out, int out_size, void* d_ws, size_t ws_size,
                              hipStream_t stream)
{
    const float* x    = (const float*)d_in[0];
    const void*  mask = d_in[1];
    const float* Wq   = (const float*)d_in[2];
    const float* bq   = (const float*)d_in[3];
    const float* Wk   = (const float*)d_in[4];
    const float* bk   = (const float*)d_in[5];
    const float* Wv   = (const float*)d_in[6];
    const float* bv   = (const float*)d_in[7];
    const float* Wo   = (const float*)d_in[8];
    const float* bo   = (const float*)d_in[9];
    float* out = (float*)d_out;

    char* ws = (char*)d_ws;
    size_t off = 0;
    float* maskf = (float*)(ws + off); off += (size_t)BB*SS*4;          // 128 KB
    short* Q     = (short*)(ws + off); off += (size_t)BB*HH*SS*DHP*2;   // 16 MB
    short* Kc    = (short*)(ws + off); off += (size_t)BB*HH*SS*DHP*2;   // 16 MB (Af aliases)
    short* Vc    = (short*)(ws + off); off += (size_t)BB*HH*SS*DHP*2;   // 16 MB
    short* KF    = (short*)(ws + off); off += (size_t)BB*HH*SS*DHP*2;   // 16 MB
    short* VF    = (short*)(ws + off); off += (size_t)BB*HH*SS*DHP*2;   // 16 MB
    short* xF    = (short*)(ws + off); off += (size_t)BB*SS*DD*2;       // 12.6 MB
    short* WqF   = (short*)(ws + off); off += (size_t)HH*DHP*DD*2;
    short* WkF   = (short*)(ws + off); off += (size_t)HH*DHP*DD*2;
    short* WvF   = (short*)(ws + off); off += (size_t)HH*DHP*DD*2;
    short* WoFh  = (short*)(ws + off); off += (size_t)DD*DD*2;
    short* WoFl  = (short*)(ws + off); off += (size_t)DD*DD*2;
    int*   fwd   = (int*)  (ws + off); off += (size_t)BB*SS*4;          // 128 KB
    int*   cnt   = (int*)  (ws + off); off += 256;

    // Af (12 MB) aliases Kc (16 MB): Kc is dead after kvprep, Af written by flash
    short* Af = Kc;

    prep_kernel<<<dim3(720), dim3(256), 0, stream>>>(
        Wq, Wk, Wv, Wo, WqF, WkF, WvF, WoFh, WoFl);
    xprep_kernel<<<dim3(512), dim3(256), 0, stream>>>(x, xF);
    scan_kernel<<<dim3(BB), dim3(1024), 0, stream>>>(mask, maskf, fwd, cnt);
    proj_kernel<<<dim3(512, 4), dim3(256), 0, stream>>>(
        xF, bq, bk, bv, WqF, WkF, WvF, maskf, Q, Kc, Vc);
    kvprep_kernel<<<dim3(256, 8), dim3(256), 0, stream>>>(
        Kc, Vc, fwd, cnt, KF, VF);
    flash_kernel<<<dim3(512), dim3(256), 0, stream>>>(
        Q, KF, VF, cnt, Af);
    final_kernel<<<dim3(512, 4), dim3(256), 0, stream>>>(
        Af, WoFh, WoFl, bo, out);
}

// Round 16
// 91.940 us; speedup vs baseline: 1.2140x; 1.0968x over previous
//
#include <hip/hip_runtime.h>

typedef __attribute__((ext_vector_type(8))) short short8;
typedef __attribute__((ext_vector_type(4))) float f32x4;
typedef __attribute__((ext_vector_type(16))) float f32x16;
typedef __attribute__((ext_vector_type(2))) unsigned uint2v;
typedef __attribute__((ext_vector_type(4))) unsigned uint4v;

#define MFMA16(a,b,c) __builtin_amdgcn_mfma_f32_16x16x32_bf16((a),(b),(c),0,0,0)
#define MFMA32(a,b,c) __builtin_amdgcn_mfma_f32_32x32x16_bf16((a),(b),(c),0,0,0)

#define BB 32
#define SS 1024
#define DD 192
#define HH 8
#define DHP 32   // padded head dim (24 -> 32); col 31 = mask-bias, col 24 of V = ones

// Q pre-scale: log2(e) / sqrt(24)  -> exp2(S) == softmax numerator
#define SCALE_Q 0.294468266742895f

__device__ __forceinline__ short nb(float f) {
    __bf16 h = (__bf16)f;
    return __builtin_bit_cast(short, h);
}
__device__ __forceinline__ float bf2f(short s) {
    union { unsigned u; float f; } v; v.u = ((unsigned)(unsigned short)s) << 16;
    return v.f;
}
__device__ __forceinline__ unsigned pk2(float a, float b) {
    unsigned short lo = __builtin_bit_cast(unsigned short, (__bf16)a);
    unsigned short hi = __builtin_bit_cast(unsigned short, (__bf16)b);
    return (unsigned)lo | ((unsigned)hi << 16);
}

// ---------------- setup: weights-frag + x-frag + mask scan, fused ----------------
// blocks [0,720): weight layouts; [720,1232): xprep; [1232,1264): scan (256 thr, 4 s/thr)
#define NBLK_PREP 720
#define NBLK_XPREP 512
__global__ __launch_bounds__(256) void setup_kernel(
    const float* __restrict__ Wq, const float* __restrict__ Wk, const float* __restrict__ Wv,
    const float* __restrict__ Wo, const float* __restrict__ x, const void* __restrict__ mask_raw,
    short* __restrict__ WqF, short* __restrict__ WkF, short* __restrict__ WvF,
    short* __restrict__ WoFh, short* __restrict__ xF,
    float* __restrict__ maskf, int* __restrict__ fwd, int* __restrict__ cnt)
{
    __shared__ short lds[64][200];   // xprep staging; scan aliases first 16 B
    int bid = blockIdx.x;
    int t = threadIdx.x;

    if (bid < NBLK_PREP) {
        int idx = bid * 256 + t;
        const int NWX = 3 * HH * DHP * DD;     // 147456
        const int NWO = DD * DD;               // 36864
        if (idx < NWX) {
            int mat = idx / (HH * DHP * DD);
            int jj  = idx % (HH * DHP * DD);
            int h   = jj / (DHP * DD);
            int rem = jj % (DHP * DD);
            int e   = rem / DD;
            int d   = rem % DD;
            const float* W = (mat == 0) ? Wq : (mat == 1) ? Wk : Wv;
            short* WF      = (mat == 0) ? WqF : (mat == 1) ? WkF : WvF;
            float val = (e < 24) ? W[(h * DD + d) * 24 + e] : 0.f;
            int nt = e & 1, cc = e >> 1;
            int kk = d >> 5, g = (d >> 3) & 3, ee = d & 7;
            WF[(size_t)((((h*2+nt)*6 + kk)*64) + g*16 + cc)*8 + ee] = nb(val);
        } else if (idx < NWX + NWO) {
            int j = idx - NWX;
            int n = j / DD, k = j % DD;
            int nn = n >> 4, cc = n & 15;
            int kk = k >> 5, g = (k >> 3) & 3, ee = k & 7;
            WoFh[(size_t)(((nn*6 + kk)*64) + g*16 + cc)*8 + ee] = nb(Wo[k * DD + n]);
        }
    } else if (bid < NBLK_PREP + NBLK_XPREP) {
        // ---- xprep: x (f32) -> xF bf16 A-fragment order ----
        int xb = bid - NBLK_PREP;
        int r0 = xb * 64;
        #pragma unroll
        for (int i = 0; i < 12; i++) {
            int idx = i * 256 + t;
            int row = idx / 48;
            int colf = (idx % 48) * 4;
            float4 f = *(const float4*)(x + ((size_t)(r0 + row)) * DD + colf);
            lds[row][colf + 0] = nb(f.x);
            lds[row][colf + 1] = nb(f.y);
            lds[row][colf + 2] = nb(f.z);
            lds[row][colf + 3] = nb(f.w);
        }
        __syncthreads();
        int w = t >> 6, lane = t & 63, c = lane & 15, g = lane >> 4;
        short* outb = xF + (size_t)(xb * 4 + w) * 6 * 512;
        #pragma unroll
        for (int kk = 0; kk < 6; kk++) {
            short8 o = *(const short8*)&lds[w * 16 + c][kk * 32 + g * 8];
            *(short8*)(outb + kk * 512 + (size_t)lane * 8) = o;
        }
    } else {
        // ---- scan: mask normalize + per-batch stable compaction (fwd) ----
        int b = bid - NBLK_PREP - NBLK_XPREP;
        int lane = t & 63, wv = t >> 6;
        int* wsu = (int*)&lds[0][0];

        const unsigned* mw = (const unsigned*)mask_raw;
        bool all01 = true, allf = true;
        #pragma unroll
        for (int i = 0; i < 16; i++) {
            unsigned w = mw[i];
            all01 = all01 && (w <= 1u);
            allf  = allf  && (w == 0u || w == 0x3F800000u);
        }
        int s0 = t * 4;
        bool m[4];
        #pragma unroll
        for (int j = 0; j < 4; j++) {
            int idx = b * SS + s0 + j;
            bool mm;
            if (all01)      mm = (mw[idx] != 0u);
            else if (allf)  mm = (((const float*)mask_raw)[idx] != 0.f);
            else            mm = (((const unsigned char*)mask_raw)[idx] != 0);
            m[j] = mm;
            maskf[idx] = mm ? 1.f : 0.f;
        }
        int cnt4 = (int)m[0] + (int)m[1] + (int)m[2] + (int)m[3];
        int pref = cnt4;
        #pragma unroll
        for (int d = 1; d < 64; d <<= 1) {
            int o = __shfl_up(pref, d, 64);
            if (lane >= d) pref += o;
        }
        int waveExcl = pref - cnt4;
        if (lane == 63) wsu[wv] = pref;   // wave total
        __syncthreads();
        int waveOff = 0, totalU = 0;
        #pragma unroll
        for (int i = 0; i < 4; i++) {
            int v = wsu[i];
            if (i < wv) waveOff += v;
            totalU += v;
        }
        int pu = waveOff + waveExcl;   // unmasked count before this thread's span
        #pragma unroll
        for (int j = 0; j < 4; j++) {
            int s = s0 + j;
            if (m[j]) { fwd[b * SS + pu] = s; pu++; }
            else      { fwd[b * SS + totalU + (s - pu)] = s; }
        }
        if (t == 0) cnt[b] = totalU;
    }
}

// ---------------- proj: Q/K/V = xF @ W + b via MFMA, NATURAL row order ----------------
// blockIdx.y = head — 4096 blocks = 16/CU for store-latency hiding.
// Q[:,31] = 1.0; Kc[:,31] = mask ? 0 : -1e30; Vc[:,24] = 1.0 (denominator column)
__global__ __launch_bounds__(256) void proj_kernel(
    const short* __restrict__ xF,
    const float* __restrict__ bq, const float* __restrict__ bk, const float* __restrict__ bv,
    const short* __restrict__ WqF, const short* __restrict__ WkF, const short* __restrict__ WvF,
    const float* __restrict__ maskf,
    short* __restrict__ Q, short* __restrict__ Kc, short* __restrict__ Vc)
{
    int tid = threadIdx.x;
    int lane = tid & 63, w = tid >> 6;
    int c = lane & 15, g = lane >> 4;
    int r0 = blockIdx.x * 64 + w * 16;
    int h = blockIdx.y;

    int b_ = r0 >> 10;
    int s0 = (r0 & 1023) + g * 4;
    int bh = b_ * HH + h;

    short8 a[6];
    const short* xfb = xF + (size_t)(r0 >> 4) * 6 * 512 + (size_t)lane * 8;
    #pragma unroll
    for (int kk = 0; kk < 6; kk++)
        a[kk] = *(const short8*)(xfb + kk * 512);

    float mrow[4];
    #pragma unroll
    for (int r = 0; r < 4; r++) mrow[r] = maskf[b_ * SS + s0 + r];

    #pragma unroll
    for (int mat = 0; mat < 3; mat++) {
        const short* WF   = (mat==0)?WqF:(mat==1)?WkF:WvF;
        const float* bias = (mat==0)?bq:(mat==1)?bk:bv;

        f32x4 acc0 = {0.f,0.f,0.f,0.f};   // actual col 2c
        f32x4 acc1 = {0.f,0.f,0.f,0.f};   // actual col 2c+1
        const short* Wp0 = WF + (size_t)((h*2+0)*6) * 512 + lane * 8;
        const short* Wp1 = WF + (size_t)((h*2+1)*6) * 512 + lane * 8;
        #pragma unroll
        for (int kk = 0; kk < 6; kk++) {
            short8 b0 = *(const short8*)(Wp0 + kk * 512);
            short8 b1 = *(const short8*)(Wp1 + kk * 512);
            acc0 = MFMA16(a[kk], b0, acc0);
            acc1 = MFMA16(a[kk], b1, acc1);
        }
        float bv0 = 0.f, bv1 = 0.f;
        if (2*c < 24) {
            float2 bb = *(const float2*)(bias + h * 24 + 2 * c);
            bv0 = bb.x; bv1 = bb.y;
        }

        if (mat == 0) {
            #pragma unroll
            for (int r = 0; r < 4; r++) {
                float v0 = (acc0[r] + bv0) * SCALE_Q;
                float v1 = (c == 15) ? 1.0f : (acc1[r] + bv1) * SCALE_Q;
                *(unsigned*)(Q + ((size_t)bh * SS + s0 + r) * DHP + 2*c) = pk2(v0, v1);
            }
        } else if (mat == 1) {
            #pragma unroll
            for (int r = 0; r < 4; r++) {
                float v0 = acc0[r] + bv0;
                float v1 = (c == 15) ? ((mrow[r] != 0.f) ? 0.f : -1e30f)
                                     : (acc1[r] + bv1);
                *(unsigned*)(Kc + ((size_t)bh * SS + s0 + r) * DHP + 2*c) = pk2(v0, v1);
            }
        } else {
            #pragma unroll
            for (int r = 0; r < 4; r++) {
                float v0 = (c == 12) ? 1.0f : (acc0[r] + bv0);  // col 24 = ones
                float v1 = acc1[r] + bv1;
                *(unsigned*)(Vc + ((size_t)bh * SS + s0 + r) * DHP + 2*c) = pk2(v0, v1);
            }
        }
    }
}

// ---------------- kvprep: gather compacted rows, emit KF/VF fragment-tile layouts ----------------
__global__ __launch_bounds__(256) void kvprep_kernel(
    const short* __restrict__ Kc, const short* __restrict__ Vc,
    const int* __restrict__ fwd, const int* __restrict__ cnt,
    short* __restrict__ KF, short* __restrict__ VF)
{
    int bh = blockIdx.x, c4 = blockIdx.y;
    int b = bh >> 3;
    int nt32 = ((cnt[b] + 31) >> 5) << 5;
    int row0 = c4 * 128;
    if (row0 >= nt32) return;

    __shared__ short lds[128][40];   // 80B row pitch (16B-aligned)
    int t = threadIdx.x;
    int srow[2];

    #pragma unroll
    for (int p = 0; p < 2; p++) {
        int j = p * 64 + (t >> 2);
        int part = t & 3;
        int s = fwd[b * SS + row0 + j];
        srow[p] = s;
        *(short8*)&lds[j][part * 8] =
            *(const short8*)(Kc + ((size_t)bh * SS + s) * DHP + part * 8);
    }
    __syncthreads();

    int tile_l = t >> 6, L = t & 63, l31 = L & 31, hi = L >> 5;
    short* kf0 = KF + (size_t)bh * SS * DHP + (size_t)(row0 / 32 + tile_l) * 1024;
    #pragma unroll
    for (int i = 0; i < 2; i++) {
        short8 o = *(const short8*)&lds[tile_l * 32 + l31][i * 16 + hi * 8];
        *(short8*)(kf0 + i * 512 + (size_t)L * 8) = o;
    }
    __syncthreads();

    #pragma unroll
    for (int p = 0; p < 2; p++) {
        int j = p * 64 + (t >> 2);
        int part = t & 3;
        *(short8*)&lds[j][part * 8] =
            *(const short8*)(Vc + ((size_t)bh * SS + srow[p]) * DHP + part * 8);
    }
    __syncthreads();

    short* vf0 = VF + (size_t)bh * SS * DHP + (size_t)(row0 / 32 + tile_l) * 1024;
    #pragma unroll
    for (int i = 0; i < 2; i++) {
        short8 o;
        #pragma unroll
        for (int j2 = 0; j2 < 8; j2++)
            o[j2] = lds[tile_l * 32 + i * 16 + hi * 8 + j2][l31];
        *(short8*)(vf0 + i * 512 + (size_t)L * 8) = o;
    }
}

// ---------------- flash attention (swapped QK^T, in-register softmax) ----------------
__device__ __forceinline__ void fproc(const f32x16& S, f32x16& acc,
                                      short8 v0, short8 v1)
{
    float p[16];
    #pragma unroll
    for (int r = 0; r < 16; r++) p[r] = __builtin_amdgcn_exp2f(S[r]);

    unsigned c01 = pk2(p[0],  p[1]);
    unsigned c23 = pk2(p[2],  p[3]);
    unsigned c45 = pk2(p[4],  p[5]);
    unsigned c67 = pk2(p[6],  p[7]);
    unsigned c89 = pk2(p[8],  p[9]);
    unsigned cab = pk2(p[10], p[11]);
    unsigned ccd = pk2(p[12], p[13]);
    unsigned cef = pk2(p[14], p[15]);

    uint2v s0 = __builtin_amdgcn_permlane32_swap(c01, c45, false, false);
    uint2v s1 = __builtin_amdgcn_permlane32_swap(c23, c67, false, false);
    uint2v s2 = __builtin_amdgcn_permlane32_swap(c89, ccd, false, false);
    uint2v s3 = __builtin_amdgcn_permlane32_swap(cab, cef, false, false);

    uint4v w0v = { s0.x, s1.x, s0.y, s1.y };   // PV A-frag, kpos tile 0..15
    uint4v w1v = { s2.x, s3.x, s2.y, s3.y };   // kpos tile 16..31
    short8 pa0 = __builtin_bit_cast(short8, w0v);
    short8 pa1 = __builtin_bit_cast(short8, w1v);

    acc = MFMA32(pa0, v0, acc);
    acc = MFMA32(pa1, v1, acc);
}

// grid 512 = 256 bh x 2 qb; 4 q-chunks per wave (ILP-4 per K/V load)
__global__ __launch_bounds__(256, 2) void flash_kernel(
    const short* __restrict__ Q, const short* __restrict__ KF, const short* __restrict__ VF,
    const int* __restrict__ cnt, short* __restrict__ Af)
{
    __shared__ float llds[4][4][32];

    int idx = blockIdx.x;
    int bh = idx & 255;
    int qb = idx >> 8;          // 0..1
    int b = bh >> 3, h = bh & 7;

    int tid = threadIdx.x;
    int lane = tid & 63, w = tid >> 6;
    int l31 = lane & 31;
    int hi = lane >> 5;

    int nt = (cnt[b] + 31) >> 5;

    int qr0 = qb * 512 + w * 32;   // chunks at qr0 + cc*128

    short8 qf[4][2];
    #pragma unroll
    for (int cc = 0; cc < 4; cc++) {
        const short* Qp = Q + ((size_t)bh * SS + qr0 + cc * 128 + l31) * DHP + hi * 8;
        qf[cc][0] = *(const short8*)Qp;
        qf[cc][1] = *(const short8*)(Qp + 16);
    }

    const short* Kp = KF + (size_t)bh * SS * DHP + (size_t)lane * 8;
    const short* Vp = VF + (size_t)bh * SS * DHP + (size_t)lane * 8;

    f32x16 acc[4], Z16;
    #pragma unroll
    for (int r = 0; r < 16; r++) {
        acc[0][r] = 0.f; acc[1][r] = 0.f; acc[2][r] = 0.f; acc[3][r] = 0.f;
        Z16[r] = 0.f;
    }

    short8 k0 = *(const short8*)(Kp);
    short8 k1 = *(const short8*)(Kp + 512);
    short8 v0 = *(const short8*)(Vp);
    short8 v1 = *(const short8*)(Vp + 512);

    for (int kt = 0; kt < nt; kt++) {
        Kp += 1024;
        Vp += 1024;
        short8 nk0 = *(const short8*)(Kp);
        short8 nk1 = *(const short8*)(Kp + 512);
        short8 nv0 = *(const short8*)(Vp);
        short8 nv1 = *(const short8*)(Vp + 512);

        #pragma unroll
        for (int cc = 0; cc < 4; cc++) {
            f32x16 S = MFMA32(k0, qf[cc][0], Z16);
            S = MFMA32(k1, qf[cc][1], S);   // includes mask bias via channel e=31
            fproc(S, acc[cc], v0, v1);
        }

        k0 = nk0; k1 = nk1; v0 = nv0; v1 = nv1;
    }

    if (l31 == 24) {
        #pragma unroll
        for (int cc = 0; cc < 4; cc++) {
            #pragma unroll
            for (int r = 0; r < 16; r++) {
                int row = (r & 3) + 8 * (r >> 2) + 4 * hi;
                llds[w][cc][row] = __builtin_amdgcn_rcpf(acc[cc][r]);
            }
        }
    }
    __builtin_amdgcn_wave_barrier();

    if (l31 < 24) {
        int d = h * 24 + l31;
        size_t fcol = (size_t)((d >> 5) * 4 + ((d >> 3) & 3)) * 128 + (d & 7);
        #pragma unroll
        for (int cc = 0; cc < 4; cc++) {
            int grp = (b * SS + qr0 + cc * 128) >> 4;
            short* op = Af + (size_t)grp * 3072 + fcol;   // 3072 = 24*128
            #pragma unroll
            for (int r = 0; r < 16; r++) {
                int row = (r & 3) + 8 * (r >> 2) + 4 * hi;
                size_t off = (size_t)(r >> 3) * 3072 + (size_t)(row & 15) * 8;
                op[off] = nb(acc[cc][r] * llds[w][cc][row]);
            }
        }
    }
}

// ---------------- final: out = attn(bf16) @ Wo(bf16) + bo ----------------
// blockIdx.y selects quarter of the 12 output n-tiles — 2048 blocks = 8/CU
__global__ __launch_bounds__(256) void final_kernel(
    const short* __restrict__ Af,
    const short* __restrict__ WoFh,
    const float* __restrict__ bo, float* __restrict__ out)
{
    int tid = threadIdx.x;
    int lane = tid & 63, w = tid >> 6;
    int c = lane & 15, g = lane >> 4;
    int r0 = blockIdx.x * 64 + w * 16;
    int n0 = blockIdx.y * 3;

    short8 a[6];
    #pragma unroll
    for (int kk = 0; kk < 6; kk++)
        a[kk] = *(const short8*)(Af + ((size_t)(r0 >> 4) * 24 + kk*4 + g) * 128 + c * 8);

    f32x4 acc[3];
    #pragma unroll
    for (int n = 0; n < 3; n++) acc[n] = (f32x4){0.f,0.f,0.f,0.f};

    #pragma unroll
    for (int kk = 0; kk < 6; kk++) {
        #pragma unroll
        for (int n = 0; n < 3; n++) {
            short8 bh = *(const short8*)(WoFh + (size_t)((n0+n)*6 + kk) * 512 + lane * 8);
            acc[n] = MFMA16(a[kk], bh, acc[n]);
        }
    }

    #pragma unroll
    for (int n = 0; n < 3; n++) {
        int col = (n0+n)*16 + c;
        float bv = bo[col];
        #pragma unroll
        for (int r = 0; r < 4; r++) {
            out[(size_t)(r0 + g*4 + r) * DD + col] = acc[n][r] + bv;
        }
    }
}

extern "C" void kernel_launch(void* const* d_in, const int* in_sizes, int n_in,
                              void* d_out, int out_size, void* d_ws, size_t ws_size,
                              hipStream_t stream)
{
    const float* x    = (const float*)d_in[0];
    const void*  mask = d_in[1];
    const float* Wq   = (const float*)d_in[2];
    const float* bq   = (const float*)d_in[3];
    const float* Wk   = (const float*)d_in[4];
    const float* bk   = (const float*)d_in[5];
    const float* Wv   = (const float*)d_in[6];
    const float* bv   = (const float*)d_in[7];
    const float* Wo   = (const float*)d_in[8];
    const float* bo   = (const float*)d_in[9];
    float* out = (float*)d_out;

    char* ws = (char*)d_ws;
    size_t off = 0;
    float* maskf = (float*)(ws + off); off += (size_t)BB*SS*4;          // 128 KB
    short* Q     = (short*)(ws + off); off += (size_t)BB*HH*SS*DHP*2;   // 16 MB
    short* Kc    = (short*)(ws + off); off += (size_t)BB*HH*SS*DHP*2;   // 16 MB (Af aliases)
    short* Vc    = (short*)(ws + off); off += (size_t)BB*HH*SS*DHP*2;   // 16 MB
    short* KF    = (short*)(ws + off); off += (size_t)BB*HH*SS*DHP*2;   // 16 MB
    short* VF    = (short*)(ws + off); off += (size_t)BB*HH*SS*DHP*2;   // 16 MB
    short* xF    = (short*)(ws + off); off += (size_t)BB*SS*DD*2;       // 12.6 MB
    short* WqF   = (short*)(ws + off); off += (size_t)HH*DHP*DD*2;
    short* WkF   = (short*)(ws + off); off += (size_t)HH*DHP*DD*2;
    short* WvF   = (short*)(ws + off); off += (size_t)HH*DHP*DD*2;
    short* WoFh  = (short*)(ws + off); off += (size_t)DD*DD*2;
    int*   fwd   = (int*)  (ws + off); off += (size_t)BB*SS*4;          // 128 KB
    int*   cnt   = (int*)  (ws + off); off += 256;

    // Af (12 MB) aliases Kc (16 MB): Kc is dead after kvprep, Af written by flash
    short* Af = Kc;

    setup_kernel<<<dim3(NBLK_PREP + NBLK_XPREP + BB), dim3(256), 0, stream>>>(
        Wq, Wk, Wv, Wo, x, mask, WqF, WkF, WvF, WoFh, xF, maskf, fwd, cnt);
    proj_kernel<<<dim3(512, 8), dim3(256), 0, stream>>>(
        xF, bq, bk, bv, WqF, WkF, WvF, maskf, Q, Kc, Vc);
    kvprep_kernel<<<dim3(256, 8), dim3(256), 0, stream>>>(
        Kc, Vc, fwd, cnt, KF, VF);
    flash_kernel<<<dim3(512), dim3(256), 0, stream>>>(
        Q, KF, VF, cnt, Af);
    final_kernel<<<dim3(512, 4), dim3(256), 0, stream>>>(
        Af, WoFh, bo, out);
}

// Round 17
// 89.134 us; speedup vs baseline: 1.2522x; 1.0315x over previous
//
#include <hip/hip_runtime.h>

typedef __attribute__((ext_vector_type(8))) short short8;
typedef __attribute__((ext_vector_type(4))) float f32x4;
typedef __attribute__((ext_vector_type(16))) float f32x16;
typedef __attribute__((ext_vector_type(2))) unsigned uint2v;
typedef __attribute__((ext_vector_type(4))) unsigned uint4v;

#define MFMA16(a,b,c) __builtin_amdgcn_mfma_f32_16x16x32_bf16((a),(b),(c),0,0,0)
#define MFMA32(a,b,c) __builtin_amdgcn_mfma_f32_32x32x16_bf16((a),(b),(c),0,0,0)

#define BB 32
#define SS 1024
#define DD 192
#define HH 8
#define DHP 32   // padded head dim (24 -> 32); col 31 = mask-bias, col 24 of V = ones

// Q pre-scale: log2(e) / sqrt(24)  -> exp2(S) == softmax numerator
#define SCALE_Q 0.294468266742895f

__device__ __forceinline__ short nb(float f) {
    __bf16 h = (__bf16)f;
    return __builtin_bit_cast(short, h);
}
__device__ __forceinline__ unsigned pk2(float a, float b) {
    unsigned short lo = __builtin_bit_cast(unsigned short, (__bf16)a);
    unsigned short hi = __builtin_bit_cast(unsigned short, (__bf16)b);
    return (unsigned)lo | ((unsigned)hi << 16);
}

// ---------------- setup: weights-frag + x-frag + mask scan, fused ----------------
// blocks [0,720): weight layouts; [720,1232): xprep; [1232,1264): scan (256 thr, 4 s/thr)
#define NBLK_PREP 720
#define NBLK_XPREP 512
__global__ __launch_bounds__(256) void setup_kernel(
    const float* __restrict__ Wq, const float* __restrict__ Wk, const float* __restrict__ Wv,
    const float* __restrict__ Wo, const float* __restrict__ x, const void* __restrict__ mask_raw,
    short* __restrict__ WqF, short* __restrict__ WkF, short* __restrict__ WvF,
    short* __restrict__ WoFh, short* __restrict__ xF,
    float* __restrict__ maskf, int* __restrict__ fwd, int* __restrict__ cnt)
{
    __shared__ short lds[64][200];   // xprep staging; scan aliases first 16 B
    int bid = blockIdx.x;
    int t = threadIdx.x;

    if (bid < NBLK_PREP) {
        int idx = bid * 256 + t;
        const int NWX = 3 * HH * DHP * DD;     // 147456
        const int NWO = DD * DD;               // 36864
        if (idx < NWX) {
            int mat = idx / (HH * DHP * DD);
            int jj  = idx % (HH * DHP * DD);
            int h   = jj / (DHP * DD);
            int rem = jj % (DHP * DD);
            int e   = rem / DD;
            int d   = rem % DD;
            const float* W = (mat == 0) ? Wq : (mat == 1) ? Wk : Wv;
            short* WF      = (mat == 0) ? WqF : (mat == 1) ? WkF : WvF;
            float val = (e < 24) ? W[(h * DD + d) * 24 + e] : 0.f;
            int nt = e & 1, cc = e >> 1;
            int kk = d >> 5, g = (d >> 3) & 3, ee = d & 7;
            WF[(size_t)((((h*2+nt)*6 + kk)*64) + g*16 + cc)*8 + ee] = nb(val);
        } else if (idx < NWX + NWO) {
            int j = idx - NWX;
            int n = j / DD, k = j % DD;
            int nn = n >> 4, cc = n & 15;
            int kk = k >> 5, g = (k >> 3) & 3, ee = k & 7;
            WoFh[(size_t)(((nn*6 + kk)*64) + g*16 + cc)*8 + ee] = nb(Wo[k * DD + n]);
        }
    } else if (bid < NBLK_PREP + NBLK_XPREP) {
        // ---- xprep: x (f32) -> xF bf16 A-fragment order ----
        int xb = bid - NBLK_PREP;
        int r0 = xb * 64;
        #pragma unroll
        for (int i = 0; i < 12; i++) {
            int idx = i * 256 + t;
            int row = idx / 48;
            int colf = (idx % 48) * 4;
            float4 f = *(const float4*)(x + ((size_t)(r0 + row)) * DD + colf);
            lds[row][colf + 0] = nb(f.x);
            lds[row][colf + 1] = nb(f.y);
            lds[row][colf + 2] = nb(f.z);
            lds[row][colf + 3] = nb(f.w);
        }
        __syncthreads();
        int w = t >> 6, lane = t & 63, c = lane & 15, g = lane >> 4;
        short* outb = xF + (size_t)(xb * 4 + w) * 6 * 512;
        #pragma unroll
        for (int kk = 0; kk < 6; kk++) {
            short8 o = *(const short8*)&lds[w * 16 + c][kk * 32 + g * 8];
            *(short8*)(outb + kk * 512 + (size_t)lane * 8) = o;
        }
    } else {
        // ---- scan: mask normalize + per-batch stable compaction (fwd) ----
        int b = bid - NBLK_PREP - NBLK_XPREP;
        int lane = t & 63, wv = t >> 6;
        int* wsu = (int*)&lds[0][0];

        const unsigned* mw = (const unsigned*)mask_raw;
        bool all01 = true, allf = true;
        #pragma unroll
        for (int i = 0; i < 16; i++) {
            unsigned w = mw[i];
            all01 = all01 && (w <= 1u);
            allf  = allf  && (w == 0u || w == 0x3F800000u);
        }
        int s0 = t * 4;
        bool m[4];
        #pragma unroll
        for (int j = 0; j < 4; j++) {
            int idx = b * SS + s0 + j;
            bool mm;
            if (all01)      mm = (mw[idx] != 0u);
            else if (allf)  mm = (((const float*)mask_raw)[idx] != 0.f);
            else            mm = (((const unsigned char*)mask_raw)[idx] != 0);
            m[j] = mm;
            maskf[idx] = mm ? 1.f : 0.f;
        }
        int cnt4 = (int)m[0] + (int)m[1] + (int)m[2] + (int)m[3];
        int pref = cnt4;
        #pragma unroll
        for (int d = 1; d < 64; d <<= 1) {
            int o = __shfl_up(pref, d, 64);
            if (lane >= d) pref += o;
        }
        int waveExcl = pref - cnt4;
        if (lane == 63) wsu[wv] = pref;   // wave total
        __syncthreads();
        int waveOff = 0, totalU = 0;
        #pragma unroll
        for (int i = 0; i < 4; i++) {
            int v = wsu[i];
            if (i < wv) waveOff += v;
            totalU += v;
        }
        int pu = waveOff + waveExcl;
        #pragma unroll
        for (int j = 0; j < 4; j++) {
            int s = s0 + j;
            if (m[j]) { fwd[b * SS + pu] = s; pu++; }
            else      { fwd[b * SS + totalU + (s - pu)] = s; }
        }
        if (t == 0) cnt[b] = totalU;
    }
}

// ---------------- proj2: projq [0,2048) + projkv [2048,4096) ----------------
// projq: Q = xF @ Wq (natural rows, 2 heads/block). Q[:,31]=1, pre-scaled.
// projkv: per (b, head-pair, 64-compacted-row chunk): gather x rows via fwd,
//   K/V MFMA, emit KF/VF fragment-tile layouts directly. Skips chunks >= nt32.
// KF element (kpos,e): tile=kpos>>5, instr=e>>4, lane=((e>>3)&1)*32+(kpos&31), j=e&7
// VF element (kpos,e): tile=kpos>>5, instr=(kpos>>4)&1, lane=((kpos>>3)&1)*32+e, j=kpos&7
__global__ __launch_bounds__(256) void proj2_kernel(
    const float* __restrict__ x, const short* __restrict__ xF,
    const float* __restrict__ bq, const float* __restrict__ bk, const float* __restrict__ bv,
    const short* __restrict__ WqF, const short* __restrict__ WkF, const short* __restrict__ WvF,
    const float* __restrict__ maskf, const int* __restrict__ fwd, const int* __restrict__ cnt,
    short* __restrict__ Q, short* __restrict__ KF, short* __restrict__ VF)
{
    __shared__ short lds[64][200];
    __shared__ int   srows[64];
    __shared__ short klds[64][40];

    int bid = blockIdx.x;
    int t = threadIdx.x;
    int lane = t & 63, w = t >> 6;
    int c = lane & 15, g = lane >> 4;

    if (bid < 2048) {
        // ---------------- projq ----------------
        int rb = bid & 511, hp = bid >> 9;
        int r0 = rb * 64 + w * 16;
        int b_ = r0 >> 10;
        int s0 = (r0 & 1023) + g * 4;

        short8 a[6];
        const short* xfb = xF + (size_t)(r0 >> 4) * 6 * 512 + (size_t)lane * 8;
        #pragma unroll
        for (int kk = 0; kk < 6; kk++)
            a[kk] = *(const short8*)(xfb + kk * 512);

        #pragma unroll
        for (int hh = 0; hh < 2; hh++) {
            int h = hp * 2 + hh;
            int bh = b_ * HH + h;
            f32x4 acc0 = {0.f,0.f,0.f,0.f};
            f32x4 acc1 = {0.f,0.f,0.f,0.f};
            const short* Wp0 = WqF + (size_t)((h*2+0)*6) * 512 + lane * 8;
            const short* Wp1 = WqF + (size_t)((h*2+1)*6) * 512 + lane * 8;
            #pragma unroll
            for (int kk = 0; kk < 6; kk++) {
                short8 b0 = *(const short8*)(Wp0 + kk * 512);
                short8 b1 = *(const short8*)(Wp1 + kk * 512);
                acc0 = MFMA16(a[kk], b0, acc0);
                acc1 = MFMA16(a[kk], b1, acc1);
            }
            float bv0 = 0.f, bv1 = 0.f;
            if (2*c < 24) {
                float2 bb = *(const float2*)(bq + h * 24 + 2 * c);
                bv0 = bb.x; bv1 = bb.y;
            }
            #pragma unroll
            for (int r = 0; r < 4; r++) {
                float v0 = (acc0[r] + bv0) * SCALE_Q;
                float v1 = (c == 15) ? 1.0f : (acc1[r] + bv1) * SCALE_Q;
                *(unsigned*)(Q + ((size_t)bh * SS + s0 + r) * DHP + 2*c) = pk2(v0, v1);
            }
        }
        return;
    }

    // ---------------- projkv ----------------
    int kb = bid - 2048;
    int chunk = kb & 15, hp = (kb >> 4) & 3, b = kb >> 6;
    int row0 = chunk * 64;
    int nt32 = ((cnt[b] + 31) >> 5) << 5;
    if (row0 >= nt32) return;

    // gather 64 compacted rows of x (f32 -> bf16 in LDS)
    {
        int j = t >> 2, part = t & 3;
        int s = fwd[b * SS + row0 + j];
        if (part == 0) srows[j] = s;
        const float* xr = x + ((size_t)(b * SS + s)) * DD + part * 48;
        #pragma unroll
        for (int i = 0; i < 12; i++) {
            float4 f = *(const float4*)(xr + i * 4);
            int col = part * 48 + i * 4;
            *(unsigned*)&lds[j][col]     = pk2(f.x, f.y);
            *(unsigned*)&lds[j][col + 2] = pk2(f.z, f.w);
        }
    }
    __syncthreads();

    // A-fragments: wave w owns rows w*16..w*16+15
    short8 a[6];
    #pragma unroll
    for (int kk = 0; kk < 6; kk++)
        a[kk] = *(const short8*)&lds[w * 16 + c][kk * 32 + g * 8];

    float mrow[4];
    #pragma unroll
    for (int r = 0; r < 4; r++)
        mrow[r] = maskf[b * SS + srows[w * 16 + g * 4 + r]];

    int l31 = lane & 31, hi = lane >> 5;

    #pragma unroll
    for (int hh = 0; hh < 2; hh++) {
        int h = hp * 2 + hh;
        int bh = b * HH + h;

        f32x4 aK0 = {0.f,0.f,0.f,0.f}, aK1 = {0.f,0.f,0.f,0.f};
        f32x4 aV0 = {0.f,0.f,0.f,0.f}, aV1 = {0.f,0.f,0.f,0.f};
        const short* Kp0 = WkF + (size_t)((h*2+0)*6) * 512 + lane * 8;
        const short* Kp1 = WkF + (size_t)((h*2+1)*6) * 512 + lane * 8;
        const short* Vp0 = WvF + (size_t)((h*2+0)*6) * 512 + lane * 8;
        const short* Vp1 = WvF + (size_t)((h*2+1)*6) * 512 + lane * 8;
        #pragma unroll
        for (int kk = 0; kk < 6; kk++) {
            aK0 = MFMA16(a[kk], *(const short8*)(Kp0 + kk * 512), aK0);
            aK1 = MFMA16(a[kk], *(const short8*)(Kp1 + kk * 512), aK1);
            aV0 = MFMA16(a[kk], *(const short8*)(Vp0 + kk * 512), aV0);
            aV1 = MFMA16(a[kk], *(const short8*)(Vp1 + kk * 512), aV1);
        }
        float bk0 = 0.f, bk1 = 0.f, bvv0 = 0.f, bvv1 = 0.f;
        if (2*c < 24) {
            float2 kb2 = *(const float2*)(bk + h * 24 + 2 * c);
            float2 vb2 = *(const float2*)(bv + h * 24 + 2 * c);
            bk0 = kb2.x; bk1 = kb2.y; bvv0 = vb2.x; bvv1 = vb2.y;
        }

        __syncthreads();   // klds free (prev emit done)
        #pragma unroll
        for (int r = 0; r < 4; r++) {
            float v0 = aK0[r] + bk0;
            float v1 = (c == 15) ? ((mrow[r] != 0.f) ? 0.f : -1e30f) : (aK1[r] + bk1);
            *(unsigned*)&klds[w * 16 + g * 4 + r][2 * c] = pk2(v0, v1);
        }
        __syncthreads();
        if (t < 128) {   // K emit: 2 tiles
            int tt = (t >> 6) & 1, L = t & 63, l3 = L & 31, h2 = L >> 5;
            short* kf0 = KF + (size_t)bh * SS * DHP + (size_t)(row0 / 32 + tt) * 1024;
            #pragma unroll
            for (int i = 0; i < 2; i++) {
                short8 o = *(const short8*)&klds[tt * 32 + l3][i * 16 + h2 * 8];
                *(short8*)(kf0 + i * 512 + (size_t)L * 8) = o;
            }
        }
        __syncthreads();
        #pragma unroll
        for (int r = 0; r < 4; r++) {
            float v0 = (c == 12) ? 1.0f : (aV0[r] + bvv0);   // col 24 = ones
            float v1 = aV1[r] + bvv1;
            *(unsigned*)&klds[w * 16 + g * 4 + r][2 * c] = pk2(v0, v1);
        }
        __syncthreads();
        if (t < 128) {   // V emit: 2 tiles, transposed
            int tt = (t >> 6) & 1, L = t & 63, l3 = L & 31, h2 = L >> 5;
            short* vf0 = VF + (size_t)bh * SS * DHP + (size_t)(row0 / 32 + tt) * 1024;
            #pragma unroll
            for (int i = 0; i < 2; i++) {
                short8 o;
                #pragma unroll
                for (int j2 = 0; j2 < 8; j2++)
                    o[j2] = klds[tt * 32 + i * 16 + h2 * 8 + j2][l3];
                *(short8*)(vf0 + i * 512 + (size_t)L * 8) = o;
            }
        }
    }
}

// ---------------- flash attention (swapped QK^T, in-register softmax) ----------------
__device__ __forceinline__ void fproc(const f32x16& S, f32x16& acc,
                                      short8 v0, short8 v1)
{
    float p[16];
    #pragma unroll
    for (int r = 0; r < 16; r++) p[r] = __builtin_amdgcn_exp2f(S[r]);

    unsigned c01 = pk2(p[0],  p[1]);
    unsigned c23 = pk2(p[2],  p[3]);
    unsigned c45 = pk2(p[4],  p[5]);
    unsigned c67 = pk2(p[6],  p[7]);
    unsigned c89 = pk2(p[8],  p[9]);
    unsigned cab = pk2(p[10], p[11]);
    unsigned ccd = pk2(p[12], p[13]);
    unsigned cef = pk2(p[14], p[15]);

    uint2v s0 = __builtin_amdgcn_permlane32_swap(c01, c45, false, false);
    uint2v s1 = __builtin_amdgcn_permlane32_swap(c23, c67, false, false);
    uint2v s2 = __builtin_amdgcn_permlane32_swap(c89, ccd, false, false);
    uint2v s3 = __builtin_amdgcn_permlane32_swap(cab, cef, false, false);

    uint4v w0v = { s0.x, s1.x, s0.y, s1.y };   // PV A-frag, kpos tile 0..15
    uint4v w1v = { s2.x, s3.x, s2.y, s3.y };   // kpos tile 16..31
    short8 pa0 = __builtin_bit_cast(short8, w0v);
    short8 pa1 = __builtin_bit_cast(short8, w1v);

    acc = MFMA32(pa0, v0, acc);
    acc = MFMA32(pa1, v1, acc);
}

// grid 512 = 256 bh x 2 qb; 4 q-chunks per wave (ILP-4 per K/V load)
__global__ __launch_bounds__(256, 2) void flash_kernel(
    const short* __restrict__ Q, const short* __restrict__ KF, const short* __restrict__ VF,
    const int* __restrict__ cnt, short* __restrict__ Af)
{
    __shared__ float llds[4][4][32];

    int idx = blockIdx.x;
    int bh = idx & 255;
    int qb = idx >> 8;          // 0..1
    int b = bh >> 3, h = bh & 7;

    int tid = threadIdx.x;
    int lane = tid & 63, w = tid >> 6;
    int l31 = lane & 31;
    int hi = lane >> 5;

    int nt = (cnt[b] + 31) >> 5;

    int qr0 = qb * 512 + w * 32;   // chunks at qr0 + cc*128

    short8 qf[4][2];
    #pragma unroll
    for (int cc = 0; cc < 4; cc++) {
        const short* Qp = Q + ((size_t)bh * SS + qr0 + cc * 128 + l31) * DHP + hi * 8;
        qf[cc][0] = *(const short8*)Qp;
        qf[cc][1] = *(const short8*)(Qp + 16);
    }

    const short* Kp = KF + (size_t)bh * SS * DHP + (size_t)lane * 8;
    const short* Vp = VF + (size_t)bh * SS * DHP + (size_t)lane * 8;

    f32x16 acc[4], Z16;
    #pragma unroll
    for (int r = 0; r < 16; r++) {
        acc[0][r] = 0.f; acc[1][r] = 0.f; acc[2][r] = 0.f; acc[3][r] = 0.f;
        Z16[r] = 0.f;
    }

    short8 k0 = *(const short8*)(Kp);
    short8 k1 = *(const short8*)(Kp + 512);
    short8 v0 = *(const short8*)(Vp);
    short8 v1 = *(const short8*)(Vp + 512);

    for (int kt = 0; kt < nt; kt++) {
        Kp += 1024;
        Vp += 1024;
        short8 nk0 = *(const short8*)(Kp);
        short8 nk1 = *(const short8*)(Kp + 512);
        short8 nv0 = *(const short8*)(Vp);
        short8 nv1 = *(const short8*)(Vp + 512);

        #pragma unroll
        for (int cc = 0; cc < 4; cc++) {
            f32x16 S = MFMA32(k0, qf[cc][0], Z16);
            S = MFMA32(k1, qf[cc][1], S);   // includes mask bias via channel e=31
            fproc(S, acc[cc], v0, v1);
        }

        k0 = nk0; k1 = nk1; v0 = nv0; v1 = nv1;
    }

    if (l31 == 24) {
        #pragma unroll
        for (int cc = 0; cc < 4; cc++) {
            #pragma unroll
            for (int r = 0; r < 16; r++) {
                int row = (r & 3) + 8 * (r >> 2) + 4 * hi;
                llds[w][cc][row] = __builtin_amdgcn_rcpf(acc[cc][r]);
            }
        }
    }
    __builtin_amdgcn_wave_barrier();

    if (l31 < 24) {
        int d = h * 24 + l31;
        size_t fcol = (size_t)((d >> 5) * 4 + ((d >> 3) & 3)) * 128 + (d & 7);
        #pragma unroll
        for (int cc = 0; cc < 4; cc++) {
            int grp = (b * SS + qr0 + cc * 128) >> 4;
            short* op = Af + (size_t)grp * 3072 + fcol;   // 3072 = 24*128
            #pragma unroll
            for (int r = 0; r < 16; r++) {
                int row = (r & 3) + 8 * (r >> 2) + 4 * hi;
                size_t off = (size_t)(r >> 3) * 3072 + (size_t)(row & 15) * 8;
                op[off] = nb(acc[cc][r] * llds[w][cc][row]);
            }
        }
    }
}

// ---------------- final: out = attn(bf16) @ Wo(bf16) + bo ----------------
__global__ __launch_bounds__(256) void final_kernel(
    const short* __restrict__ Af,
    const short* __restrict__ WoFh,
    const float* __restrict__ bo, float* __restrict__ out)
{
    int tid = threadIdx.x;
    int lane = tid & 63, w = tid >> 6;
    int c = lane & 15, g = lane >> 4;
    int r0 = blockIdx.x * 64 + w * 16;
    int n0 = blockIdx.y * 3;

    short8 a[6];
    #pragma unroll
    for (int kk = 0; kk < 6; kk++)
        a[kk] = *(const short8*)(Af + ((size_t)(r0 >> 4) * 24 + kk*4 + g) * 128 + c * 8);

    f32x4 acc[3];
    #pragma unroll
    for (int n = 0; n < 3; n++) acc[n] = (f32x4){0.f,0.f,0.f,0.f};

    #pragma unroll
    for (int kk = 0; kk < 6; kk++) {
        #pragma unroll
        for (int n = 0; n < 3; n++) {
            short8 bh = *(const short8*)(WoFh + (size_t)((n0+n)*6 + kk) * 512 + lane * 8);
            acc[n] = MFMA16(a[kk], bh, acc[n]);
        }
    }

    #pragma unroll
    for (int n = 0; n < 3; n++) {
        int col = (n0+n)*16 + c;
        float bv = bo[col];
        #pragma unroll
        for (int r = 0; r < 4; r++) {
            out[(size_t)(r0 + g*4 + r) * DD + col] = acc[n][r] + bv;
        }
    }
}

extern "C" void kernel_launch(void* const* d_in, const int* in_sizes, int n_in,
                              void* d_out, int out_size, void* d_ws, size_t ws_size,
                              hipStream_t stream)
{
    const float* x    = (const float*)d_in[0];
    const void*  mask = d_in[1];
    const float* Wq   = (const float*)d_in[2];
    const float* bq   = (const float*)d_in[3];
    const float* Wk   = (const float*)d_in[4];
    const float* bk   = (const float*)d_in[5];
    const float* Wv   = (const float*)d_in[6];
    const float* bv   = (const float*)d_in[7];
    const float* Wo   = (const float*)d_in[8];
    const float* bo   = (const float*)d_in[9];
    float* out = (float*)d_out;

    char* ws = (char*)d_ws;
    size_t off = 0;
    float* maskf = (float*)(ws + off); off += (size_t)BB*SS*4;          // 128 KB
    short* Q     = (short*)(ws + off); off += (size_t)BB*HH*SS*DHP*2;   // 16 MB
    short* KF    = (short*)(ws + off); off += (size_t)BB*HH*SS*DHP*2;   // 16 MB
    short* VF    = (short*)(ws + off); off += (size_t)BB*HH*SS*DHP*2;   // 16 MB
    short* Af    = (short*)(ws + off); off += (size_t)BB*SS*DD*2;       // 12 MB
    short* xF    = (short*)(ws + off); off += (size_t)BB*SS*DD*2;       // 12.6 MB
    short* WqF   = (short*)(ws + off); off += (size_t)HH*DHP*DD*2;
    short* WkF   = (short*)(ws + off); off += (size_t)HH*DHP*DD*2;
    short* WvF   = (short*)(ws + off); off += (size_t)HH*DHP*DD*2;
    short* WoFh  = (short*)(ws + off); off += (size_t)DD*DD*2;
    int*   fwd   = (int*)  (ws + off); off += (size_t)BB*SS*4;          // 128 KB
    int*   cnt   = (int*)  (ws + off); off += 256;

    setup_kernel<<<dim3(NBLK_PREP + NBLK_XPREP + BB), dim3(256), 0, stream>>>(
        Wq, Wk, Wv, Wo, x, mask, WqF, WkF, WvF, WoFh, xF, maskf, fwd, cnt);
    proj2_kernel<<<dim3(4096), dim3(256), 0, stream>>>(
        x, xF, bq, bk, bv, WqF, WkF, WvF, maskf, fwd, cnt, Q, KF, VF);
    flash_kernel<<<dim3(512), dim3(256), 0, stream>>>(
        Q, KF, VF, cnt, Af);
    final_kernel<<<dim3(512, 4), dim3(256), 0, stream>>>(
        Af, WoFh, bo, out);
}